// Round 6
// baseline (717.399 us; speedup 1.0000x reference)
//
#include <hip/hip_runtime.h>
#include <hip/hip_bf16.h>
#include <math.h>

// Problem constants
#define NBATCH 4
#define TQD 4096
#define TBD 2048
#define CDIM 512
#define NH 8
#define HD 64
#define NINNER 2048

using short8 = __attribute__((ext_vector_type(8))) short;
using f32x4  = __attribute__((ext_vector_type(4))) float;

__device__ __forceinline__ float b2f(short s) {
  return __uint_as_float(((unsigned)(unsigned short)s) << 16);
}
__device__ __forceinline__ short f2b(float f) {
  unsigned u = __float_as_uint(f);
  return (short)((u + 0x7FFFu + ((u >> 16) & 1u)) >> 16);
}
__device__ __forceinline__ unsigned pk2(float a, float b) {
  float2 t; t.x = a; t.y = b;
  __hip_bfloat162 h = __float22bfloat162_rn(t);
  return *(unsigned*)&h;
}
__device__ __forceinline__ float gelu_fast(float x) {
  float x3 = x * x * x;
  float y2 = 1.5957691216f * (x + 0.044715f * x3);
  float e = __expf(y2);
  return x * e / (e + 1.0f);
}
__device__ __forceinline__ void gload16(const short* g, short* l) {
  __builtin_amdgcn_global_load_lds((const __attribute__((address_space(1))) void*)g,
                                   (__attribute__((address_space(3))) void*)l, 16, 0, 0);
}

// ---------------- LayerNorm (fp32 in -> bf16 out), one block per row, C=512
__launch_bounds__(256)
__global__ void ln_kernel(const float* __restrict__ x, const float* __restrict__ g,
                          const float* __restrict__ b, short* __restrict__ out)
{
  int r = blockIdx.x;
  int tid = threadIdx.x;
  float2 v = ((const float2*)(x + (size_t)r * CDIM))[tid];
  float s = v.x + v.y, s2 = v.x * v.x + v.y * v.y;
#pragma unroll
  for (int m = 1; m < 64; m <<= 1) { s += __shfl_xor(s, m); s2 += __shfl_xor(s2, m); }
  __shared__ float red[8];
  int wave = tid >> 6;
  if ((tid & 63) == 0) { red[wave] = s; red[4 + wave] = s2; }
  __syncthreads();
  s  = red[0] + red[1] + red[2] + red[3];
  s2 = red[4] + red[5] + red[6] + red[7];
  float mean = s * (1.0f / CDIM);
  float var  = s2 * (1.0f / CDIM) - mean * mean;
  float inv  = rsqrtf(var + 1e-5f);
  float2 gg = ((const float2*)g)[tid];
  float2 bb = ((const float2*)b)[tid];
  short2 o;
  o.x = f2b((v.x - mean) * inv * gg.x + bb.x);
  o.y = f2b((v.y - mean) * inv * gg.y + bb.y);
  *((short2*)(out + (size_t)r * CDIM + 2 * tid)) = o;
}

// ---------------- batched transpose+convert: W[K][N] f32 -> Wt[N][K] bf16
struct TcvtDesc {
  const float* src[14];
  short* dst[14];
  int K[14], N[14], nblk[14];
};
__launch_bounds__(256)
__global__ void tcvt_all(TcvtDesc d)
{
  int blk = blockIdx.x, wi = 0;
  while (blk >= d.nblk[wi]) { blk -= d.nblk[wi]; wi++; }
  const float* __restrict__ W = d.src[wi];
  short* __restrict__ Wt = d.dst[wi];
  int K = d.K[wi], N = d.N[wi];
  __shared__ float t[32][33];
  int nbk = K >> 5;
  int bk = blk % nbk, bn = blk / nbk;
  int cx = threadIdx.x & 31, cy = threadIdx.x >> 5;
#pragma unroll
  for (int i = 0; i < 4; i++)
    t[cy + 8 * i][cx] = W[(size_t)(bk * 32 + cy + 8 * i) * N + bn * 32 + cx];
  __syncthreads();
#pragma unroll
  for (int i = 0; i < 4; i++)
    Wt[(size_t)(bn * 32 + cy + 8 * i) * K + bk * 32 + cx] = f2b(t[cx][cy + 8 * i]);
}

// ================= 256x256 8-phase GEMM (m201 port; BK=64, 8 waves) =========
// Even K-tiles -> buf0, odd -> buf1. Per iteration: 8 phases, each
// {ds_read subtile; stage 1 half-tile; barrier; 16 MFMA; barrier}.
// Staging stream (6 phases ahead of consumption):
//   ph0:A0(O) ph1:A1(O) ph2:B0(E+2) ph3:B1(E+2) ph4:A0(E+2) ph5:A1(E+2)
//   ph6:B0(O+2) ph7:B1(O+2)
// Publication: vmcnt(2) at ph3/ph7 TOPS (before that phase's STG) + that
// phase's barrier => tile fully landed >=1 barrier before its first read
// (O read from ph4, E+2 read from next-iter ph0). WAR: each staged region is
// >=2 barriers past its last reader. Epilogue iteration peeled (vmcnt(0)@ph3).
// EPI: 0 = bf16 + softmax per 64-chunk where col<smLimit; 1 = gelu bf16;
//      2 = residual-add fp32.
template<int EPI>
__launch_bounds__(512, 2)
__global__ void gemm256(const short* __restrict__ A, const short* __restrict__ Bt,
                        const float* __restrict__ bias, const float* __restrict__ resid,
                        void* __restrict__ outp, int M, int N, int K, int smLimit)
{
  __shared__ short As[2 * 16384];   // [buf][half(row>>7)][128][64], slot^(row&7)
  __shared__ short Bs[2 * 16384];   // [buf][kk][256][32],  slot^((row>>1)&3)
  int tid = threadIdx.x, lane = tid & 63, wave = tid >> 6;
  int l15 = lane & 15, g = lane >> 4;
  int wr = wave >> 2, wn = wave & 3;
  int nbn = N >> 8;
  int per = gridDim.x >> 3;
  int wg = (blockIdx.x & 7) * per + (blockIdx.x >> 3);
  int bm = wg / nbn, bn = wg % nbn;
  f32x4 acc[8][4] = {};

  // staging sources (inverse-swizzled cols; validated r5)
  int asl = ((lane & 7) ^ (lane >> 3)) * 8;
  int bsl = ((lane & 3) ^ ((lane >> 3) & 3)) * 8;
  const short* gA0 = A  + (size_t)(bm * 256 + wave * 16 + (lane >> 3)) * K + asl;
  const short* gB0 = Bt + (size_t)(bn * 256 + wave * 32 + (lane >> 2)) * K + bsl;
  const size_t a1off = (size_t)8 * K;    // +8 rows (2nd gload of an A half-tile)
  const size_t b1off = (size_t)16 * K;   // +16 rows (2nd gload of a B half)
  const size_t ah1   = (size_t)128 * K;  // A row-half offset
  short* lA = As + wave * 1024;
  short* lB = Bs + wave * 1024;

  // read bases (validated r5)
  int asw0 = (g ^ (l15 & 7)) * 8;
  int asw1 = ((4 + g) ^ (l15 & 7)) * 8;
  const short* raB = As + wr * 8192 + l15 * 64;
  const short* rbB = Bs + (wn * 64 + l15) * 32 + (g ^ ((l15 >> 1) & 3)) * 8;

  short8 af[4], bfr[8];
  int NT = K >> 6, NIT = NT >> 1;

#define STGA(T, h) { \
    const short* s_ = gA0 + (h) * ah1 + (size_t)(T) * 64; \
    short* d_ = lA + ((T) & 1) * 16384 + (h) * 8192; \
    gload16(s_, d_); gload16(s_ + a1off, d_ + 512); }
#define STGB(T, kk) { \
    const short* s_ = gB0 + (size_t)(T) * 64 + (kk) * 32; \
    short* d_ = lB + ((T) & 1) * 16384 + (kk) * 8192; \
    gload16(s_, d_); gload16(s_ + b1off, d_ + 512); }
#define RDB(T) { \
    const short* bp = rbB + ((T) & 1) * 16384; \
    bfr[0] = *(const short8*)(bp);               bfr[1] = *(const short8*)(bp + 512); \
    bfr[2] = *(const short8*)(bp + 1024);        bfr[3] = *(const short8*)(bp + 1536); \
    bfr[4] = *(const short8*)(bp + 8192);        bfr[5] = *(const short8*)(bp + 8192 + 512); \
    bfr[6] = *(const short8*)(bp + 8192 + 1024); bfr[7] = *(const short8*)(bp + 8192 + 1536); }
#define RDA(T, q) { \
    const short* ap = raB + ((T) & 1) * 16384 + (q) * 2048; \
    af[0] = *(const short8*)(ap + asw0); af[1] = *(const short8*)(ap + 1024 + asw0); \
    af[2] = *(const short8*)(ap + asw1); af[3] = *(const short8*)(ap + 1024 + asw1); }
#define MFMAQ(q) { \
    __builtin_amdgcn_s_setprio(1); \
    _Pragma("unroll") for (int n = 0; n < 4; n++) { \
      acc[2*(q)][n]   = __builtin_amdgcn_mfma_f32_16x16x32_bf16(bfr[n], af[0], acc[2*(q)][n], 0, 0, 0); \
      acc[2*(q)+1][n] = __builtin_amdgcn_mfma_f32_16x16x32_bf16(bfr[n], af[1], acc[2*(q)+1][n], 0, 0, 0); } \
    _Pragma("unroll") for (int n = 0; n < 4; n++) { \
      acc[2*(q)][n]   = __builtin_amdgcn_mfma_f32_16x16x32_bf16(bfr[4+n], af[2], acc[2*(q)][n], 0, 0, 0); \
      acc[2*(q)+1][n] = __builtin_amdgcn_mfma_f32_16x16x32_bf16(bfr[4+n], af[3], acc[2*(q)+1][n], 0, 0, 0); } \
    __builtin_amdgcn_s_setprio(0); }
#define BARX  { __builtin_amdgcn_s_barrier(); __builtin_amdgcn_sched_barrier(0); }
#define BAR2  { __builtin_amdgcn_s_barrier(); }
#define VMW(n) asm volatile("s_waitcnt vmcnt(" #n ")" ::: "memory");

  // prologue: T0 fully + T1's B halves (12 loads), publish T0
  STGB(0, 0); STGB(0, 1); STGA(0, 0); STGA(0, 1); STGB(1, 0); STGB(1, 1);
  VMW(4);           // allow T1's 4 B-loads outstanding; T0's 8 landed
  BAR2;

  for (int t = 0; t < NIT - 1; ++t) {
    int E = 2 * t, O = 2 * t + 1;
    RDB(E); RDA(E, 0); STGA(O, 0);     BARX; MFMAQ(0); BAR2;   // ph0
    RDA(E, 1);         STGA(O, 1);     BARX; MFMAQ(1); BAR2;   // ph1
    RDA(E, 2);         STGB(E + 2, 0); BARX; MFMAQ(2); BAR2;   // ph2
    VMW(2);                                                    // ph3: publish O
    RDA(E, 3);         STGB(E + 2, 1); BARX; MFMAQ(3); BAR2;
    RDB(O); RDA(O, 0); STGA(E + 2, 0); BARX; MFMAQ(0); BAR2;   // ph4
    RDA(O, 1);         STGA(E + 2, 1); BARX; MFMAQ(1); BAR2;   // ph5
    RDA(O, 2);         STGB(O + 2, 0); BARX; MFMAQ(2); BAR2;   // ph6
    VMW(2);                                                    // ph7: publish E+2
    RDA(O, 3);         STGB(O + 2, 1); BARX; MFMAQ(3); BAR2;
  }
  { // peeled last iteration: stage only O's A halves; drain before O reads
    int E = NT - 2, O = NT - 1;
    RDB(E); RDA(E, 0); STGA(O, 0); BARX; MFMAQ(0); BAR2;
    RDA(E, 1);         STGA(O, 1); BARX; MFMAQ(1); BAR2;
    RDA(E, 2);                     BARX; MFMAQ(2); BAR2;
    VMW(0);
    RDA(E, 3);                     BARX; MFMAQ(3); BAR2;
    RDB(O); RDA(O, 0);             BARX; MFMAQ(0); BAR2;
    RDA(O, 1);                     BARX; MFMAQ(1); BAR2;
    RDA(O, 2);                     BARX; MFMAQ(2); BAR2;
    RDA(O, 3);                     BARX; MFMAQ(3);
  }
#undef STGA
#undef STGB
#undef RDB
#undef RDA
#undef MFMAQ
#undef BARX
#undef BAR2
#undef VMW

  int row0 = bm * 256 + wr * 128, col0 = bn * 256 + wn * 64;
#pragma unroll
  for (int n = 0; n < 4; n++) {
    f32x4 bz = *(const f32x4*)(bias + col0 + n * 16 + g * 4);
#pragma unroll
    for (int m = 0; m < 8; m++)
#pragma unroll
      for (int r = 0; r < 4; r++) acc[m][n][r] += bz[r];
  }
  if (EPI == 0 && col0 < smLimit) {
#pragma unroll
    for (int m = 0; m < 8; m++) {
      float mx = acc[m][0][0];
#pragma unroll
      for (int n = 0; n < 4; n++)
#pragma unroll
        for (int r = 0; r < 4; r++) mx = fmaxf(mx, acc[m][n][r]);
      mx = fmaxf(mx, __shfl_xor(mx, 16));
      mx = fmaxf(mx, __shfl_xor(mx, 32));
      float s = 0.0f;
#pragma unroll
      for (int n = 0; n < 4; n++)
#pragma unroll
        for (int r = 0; r < 4; r++) {
          float e = __expf(acc[m][n][r] - mx);
          acc[m][n][r] = e; s += e;
        }
      s += __shfl_xor(s, 16);
      s += __shfl_xor(s, 32);
      float inv = 1.0f / s;
#pragma unroll
      for (int n = 0; n < 4; n++)
#pragma unroll
        for (int r = 0; r < 4; r++) acc[m][n][r] *= inv;
    }
  }
  if (EPI == 1) {
#pragma unroll
    for (int m = 0; m < 8; m++)
#pragma unroll
      for (int n = 0; n < 4; n++)
#pragma unroll
        for (int r = 0; r < 4; r++) acc[m][n][r] = gelu_fast(acc[m][n][r]);
  }
#pragma unroll
  for (int m = 0; m < 8; m++) {
    int row = row0 + m * 16 + l15;
#pragma unroll
    for (int n = 0; n < 4; n++) {
      size_t base = (size_t)row * N + col0 + n * 16 + g * 4;
      if (EPI == 2) {
        f32x4 rv = *(const f32x4*)(resid + base);
        f32x4 o;
#pragma unroll
        for (int r = 0; r < 4; r++) o[r] = rv[r] + acc[m][n][r];
        *(f32x4*)((float*)outp + base) = o;
      } else {
        uint2 u;
        u.x = pk2(acc[m][n][0], acc[m][n][1]);
        u.y = pk2(acc[m][n][2], acc[m][n][3]);
        *(uint2*)((unsigned short*)outp + base) = u;
      }
    }
  }
}

// ---------------- ctx += k^T v per (b,h); grid = 32*parts, atomics into zeroed ctx
#define LDC 40
__launch_bounds__(256)
__global__ void ctx_kernel(const short* __restrict__ k, const short* __restrict__ v,
                           float* __restrict__ ctx, int T, int parts, int SD)
{
  __shared__ short kT[4][64 * LDC];
  __shared__ short vT[4][64 * LDC];
  int bh = blockIdx.x & 31, part = blockIdx.x >> 5;
  int b = bh >> 3, h = bh & 7;
  int tid = threadIdx.x, lane = tid & 63, wave = tid >> 6;
  int l15 = lane & 15, g = lane >> 4;
  int tlen = T / (4 * parts);
  int tbeg = (part * 4 + wave) * tlen;
  f32x4 acc[4][4] = {};
  short* myK = kT[wave];
  short* myV = vT[wave];
  for (int t0 = tbeg; t0 < tbeg + tlen; t0 += 32) {
#pragma unroll
    for (int j = 0; j < 4; j++) {
      int c = lane + j * 64;
      int r = c >> 3, d0 = (c & 7) * 8;
      short8 kv = *(const short8*)(k + (size_t)(b * T + t0 + r) * SD + h * 64 + d0);
      short8 vv = *(const short8*)(v + (size_t)(b * T + t0 + r) * SD + h * 64 + d0);
#pragma unroll
      for (int i = 0; i < 8; i++) {
        myK[(d0 + i) * LDC + r] = kv[i];
        myV[(d0 + i) * LDC + r] = vv[i];
      }
    }
    __syncthreads();
    short8 af[4], bfr[4];
#pragma unroll
    for (int m = 0; m < 4; m++) af[m]  = *(const short8*)(myK + (m * 16 + l15) * LDC + g * 8);
#pragma unroll
    for (int n = 0; n < 4; n++) bfr[n] = *(const short8*)(myV + (n * 16 + l15) * LDC + g * 8);
#pragma unroll
    for (int m = 0; m < 4; m++)
#pragma unroll
      for (int n = 0; n < 4; n++)
        acc[m][n] = __builtin_amdgcn_mfma_f32_16x16x32_bf16(af[m], bfr[n], acc[m][n], 0, 0, 0);
    __syncthreads();
  }
  float* cp = ctx + (size_t)bh * 64 * 64;
#pragma unroll
  for (int m = 0; m < 4; m++)
#pragma unroll
    for (int n = 0; n < 4; n++)
#pragma unroll
      for (int r = 0; r < 4; r++)
        atomicAdd(cp + (m * 16 + g * 4 + r) * 64 + (n * 16 + l15), acc[m][n][r]);
}

// ---------------- column sums of softmaxed k per (b,h): ksum[bh][64]
__launch_bounds__(256)
__global__ void colsum_kernel(const short* __restrict__ k, float* __restrict__ ksum,
                              int T, int SD)
{
  int part = blockIdx.x & 7, bh = blockIdx.x >> 3;
  int b = bh >> 3, h = bh & 7;
  int d = threadIdx.x & 63, tq = threadIdx.x >> 6;
  int tlen = T >> 3, t0 = part * tlen;
  float s = 0.0f;
  for (int t = t0 + tq; t < t0 + tlen; t += 4)
    s += b2f(k[(size_t)(b * T + t) * SD + h * 64 + d]);
  atomicAdd(&ksum[bh * 64 + d], s);
}

// ---------------- out[t,:] = q[t,:] + sum_br dinv(t) * (q[t,:] @ ctx[br])
#define LQ 72
__launch_bounds__(256)
__global__ void qctx_kernel(const short* __restrict__ q,
                            const float* __restrict__ ctx,   // [nb][32][64][64]
                            const float* __restrict__ ksum,  // [nb][32][64]
                            short* __restrict__ outp, int T, int nb, int SD)
{
  __shared__ short qs[128 * LQ];
  __shared__ short cT[2][64 * LQ];
  __shared__ float dls[2][128];
  int ntb = T >> 7;
  int bh = blockIdx.x / ntb, tq = blockIdx.x % ntb;
  int b = bh >> 3, h = bh & 7;
  int tid = threadIdx.x, lane = tid & 63, wave = tid >> 6;
  int l15 = lane & 15, g = lane >> 4;
  size_t qbase = (size_t)(b * T + tq * 128) * SD + h * 64;
  size_t obase = (size_t)(b * T + tq * 128) * CDIM + h * 64;

#pragma unroll
  for (int j = 0; j < 4; j++) {
    int c = tid + j * 256;
    int r = c >> 3, d0 = (c & 7) * 8;
    *(short8*)(qs + r * LQ + d0) = *(const short8*)(q + qbase + (size_t)r * SD + d0);
  }
  for (int br = 0; br < nb; br++) {
    const float* cp = ctx + ((size_t)br * 32 + bh) * 4096;
#pragma unroll
    for (int j = 0; j < 16; j++) {
      int e2 = tid + j * 256;
      int dd = e2 >> 6, ee = e2 & 63;
      cT[br][ee * LQ + dd] = f2b(cp[e2]);
    }
  }
  __syncthreads();

  int r0 = wave * 32;
  for (int br = 0; br < nb; br++) {
    int row = r0 + (lane >> 1);
    int dbase = (lane & 1) * 32;
    const float* kp = ksum + ((size_t)br * 32 + bh) * 64 + dbase;
    float s = 0.0f;
#pragma unroll
    for (int d = 0; d < 32; d++)
      s += b2f(qs[row * LQ + dbase + d]) * kp[d];
    s += __shfl_xor(s, 1);
    if (!(lane & 1)) dls[br][row] = 1.0f / fmaxf(s, 1e-9f);
  }

  short8 af[2][2];
#pragma unroll
  for (int m = 0; m < 2; m++)
#pragma unroll
    for (int kk = 0; kk < 2; kk++)
      af[m][kk] = *(const short8*)(qs + (r0 + m * 16 + l15) * LQ + kk * 32 + g * 8);

  float ofin[2][4][4];
#pragma unroll
  for (int m = 0; m < 2; m++)
#pragma unroll
    for (int n = 0; n < 4; n++)
#pragma unroll
      for (int r = 0; r < 4; r++)
        ofin[m][n][r] = b2f(qs[(r0 + m * 16 + g * 4 + r) * LQ + n * 16 + l15]);

  for (int br = 0; br < nb; br++) {
    f32x4 acc[2][4] = {};
#pragma unroll
    for (int kk = 0; kk < 2; kk++) {
      short8 bfr[4];
#pragma unroll
      for (int n = 0; n < 4; n++)
        bfr[n] = *(const short8*)(cT[br] + (n * 16 + l15) * LQ + kk * 32 + g * 8);
#pragma unroll
      for (int m = 0; m < 2; m++)
#pragma unroll
        for (int n = 0; n < 4; n++)
          acc[m][n] = __builtin_amdgcn_mfma_f32_16x16x32_bf16(af[m][kk], bfr[n], acc[m][n], 0, 0, 0);
    }
#pragma unroll
    for (int m = 0; m < 2; m++)
#pragma unroll
      for (int n = 0; n < 4; n++)
#pragma unroll
        for (int r = 0; r < 4; r++)
          ofin[m][n][r] += dls[br][r0 + m * 16 + g * 4 + r] * acc[m][n][r];
  }

#pragma unroll
  for (int m = 0; m < 2; m++)
#pragma unroll
    for (int n = 0; n < 4; n++)
#pragma unroll
      for (int r = 0; r < 4; r++) {
        int row = r0 + m * 16 + g * 4 + r;
        int col = n * 16 + l15;
        outp[obase + (size_t)row * CDIM + col] = f2b(ofin[m][n][r]);
      }
}

extern "C" void kernel_launch(void* const* d_in, const int* in_sizes, int n_in,
                              void* d_out, int out_size, void* d_ws, size_t ws_size,
                              hipStream_t stream)
{
  (void)in_sizes; (void)n_in; (void)out_size; (void)ws_size;
  const float* x     = (const float*)d_in[0];
  const float* y0    = (const float*)d_in[1];
  const float* y1    = (const float*)d_in[2];
  const float* ln1g  = (const float*)d_in[3];
  const float* ln1b  = (const float*)d_in[4];
  const float* ln20g = (const float*)d_in[5];
  const float* ln20b = (const float*)d_in[6];
  const float* ln21g = (const float*)d_in[7];
  const float* ln21b = (const float*)d_in[8];
  const float* ln3g  = (const float*)d_in[9];
  const float* ln3b  = (const float*)d_in[10];
  const float* ln4g  = (const float*)d_in[11];
  const float* ln4b  = (const float*)d_in[12];
  const float* ln5g  = (const float*)d_in[13];
  const float* ln5b  = (const float*)d_in[14];
  const float* caqw  = (const float*)d_in[15];
  const float* caqb  = (const float*)d_in[16];
  const float* cak0w = (const float*)d_in[17];
  const float* cak0b = (const float*)d_in[18];
  const float* cav0w = (const float*)d_in[19];
  const float* cav0b = (const float*)d_in[20];
  const float* cak1w = (const float*)d_in[21];
  const float* cak1b = (const float*)d_in[22];
  const float* cav1w = (const float*)d_in[23];
  const float* cav1b = (const float*)d_in[24];
  const float* capw  = (const float*)d_in[25];
  const float* capb  = (const float*)d_in[26];
  const float* saqw  = (const float*)d_in[27];
  const float* saqb  = (const float*)d_in[28];
  const float* sakw  = (const float*)d_in[29];
  const float* sakb  = (const float*)d_in[30];
  const float* savw  = (const float*)d_in[31];
  const float* savb  = (const float*)d_in[32];
  const float* sapw  = (const float*)d_in[33];
  const float* sapb  = (const float*)d_in[34];
  const float* m1w1  = (const float*)d_in[35];
  const float* m1b1  = (const float*)d_in[36];
  const float* m1w2  = (const float*)d_in[37];
  const float* m1b2  = (const float*)d_in[38];
  const float* m2w1  = (const float*)d_in[39];
  const float* m2b1  = (const float*)d_in[40];
  const float* m2w2  = (const float*)d_in[41];
  const float* m2b2  = (const float*)d_in[42];
  float* xout = (float*)d_out;

  char* p = (char*)d_ws;
  size_t off = 0;
  auto take = [&](size_t bytes) {
    char* r = p + off;
    off += (bytes + 255) & ~(size_t)255;
    return r;
  };
  const size_t W512 = (size_t)512 * 512 * 2;
  const size_t WMLP = (size_t)2048 * 512 * 2;
  short* wt_caq   = (short*)take(W512);
  short* wt_cakv0 = (short*)take(2 * W512);       // [k;v] 1024x512
  short* wt_cakv1 = (short*)take(2 * W512);
  short* wt_cap   = (short*)take(W512);
  short* wt_saqkv = (short*)take(3 * W512);       // [q;k;v] 1536x512
  short* wt_sap   = (short*)take(W512);
  short* wt_m1w1  = (short*)take(WMLP);
  short* wt_m1w2  = (short*)take(WMLP);
  short* wt_m2w1  = (short*)take(WMLP);
  short* wt_m2w2  = (short*)take(WMLP);
  float* b_saqkv  = (float*)take(1536 * 4);
  float* b_cakv0  = (float*)take(1024 * 4);
  float* b_cakv1  = (float*)take(1024 * 4);
  short* xn   = (short*)take((size_t)16384 * 512 * 2);
  short* bufD = (short*)take((size_t)16384 * 512 * 2);
  short* big  = (short*)take((size_t)16384 * 1536 * 2);   // CA: q@0, kv@+8M shorts; SA: qkv
  short* h1   = (short*)take((size_t)16384 * 2048 * 2);
  float* ksum = (float*)take((size_t)2 * 32 * 64 * 4);
  float* ctxb = (float*)take((size_t)2 * 32 * 64 * 64 * 4);

  short* q_ca  = big;
  short* kv_ca = big + (size_t)8 * 1024 * 1024;
  short* qkv   = big;

  const int MQ  = NBATCH * TQD;   // 16384
  const int MKV = NBATCH * TBD;   // 8192

  // ---- weight transpose+convert (single batched launch) ----
  {
    TcvtDesc d;
    const float* srcs[14] = {caqw, cak0w, cav0w, cak1w, cav1w, capw,
                             saqw, sakw, savw, sapw, m1w1, m1w2, m2w1, m2w2};
    short* dsts[14] = {wt_caq, wt_cakv0, wt_cakv0 + 512 * 512,
                       wt_cakv1, wt_cakv1 + 512 * 512, wt_cap,
                       wt_saqkv, wt_saqkv + 512 * 512, wt_saqkv + 2 * 512 * 512, wt_sap,
                       wt_m1w1, wt_m1w2, wt_m2w1, wt_m2w2};
    int Ks[14] = {512,512,512,512,512,512,512,512,512,512, 512,2048,512,2048};
    int Ns[14] = {512,512,512,512,512,512,512,512,512,512, 2048,512,2048,512};
    int total = 0;
    for (int i = 0; i < 14; i++) {
      d.src[i] = srcs[i]; d.dst[i] = dsts[i]; d.K[i] = Ks[i]; d.N[i] = Ns[i];
      d.nblk[i] = (Ks[i] >> 5) * (Ns[i] >> 5);
      total += d.nblk[i];
    }
    tcvt_all<<<total, 256, 0, stream>>>(d);
  }
  // ---- bias concats ----
  hipMemcpyAsync(b_saqkv,        saqb,  512 * 4, hipMemcpyDeviceToDevice, stream);
  hipMemcpyAsync(b_saqkv + 512,  sakb,  512 * 4, hipMemcpyDeviceToDevice, stream);
  hipMemcpyAsync(b_saqkv + 1024, savb,  512 * 4, hipMemcpyDeviceToDevice, stream);
  hipMemcpyAsync(b_cakv0,        cak0b, 512 * 4, hipMemcpyDeviceToDevice, stream);
  hipMemcpyAsync(b_cakv0 + 512,  cav0b, 512 * 4, hipMemcpyDeviceToDevice, stream);
  hipMemcpyAsync(b_cakv1,        cak1b, 512 * 4, hipMemcpyDeviceToDevice, stream);
  hipMemcpyAsync(b_cakv1 + 512,  cav1b, 512 * 4, hipMemcpyDeviceToDevice, stream);

  // ---- cross-attention ----
  ln_kernel<<<MQ, 256, 0, stream>>>(x, ln1g, ln1b, xn);
  gemm256<0><<<128, 512, 0, stream>>>(xn, wt_caq, caqb, nullptr, q_ca, MQ, 512, 512, 512);
  hipMemsetAsync(ksum, 0, (size_t)2 * 32 * 64 * 4, stream);
  hipMemsetAsync(ctxb, 0, (size_t)2 * 32 * 64 * 64 * 4, stream);
  for (int br = 0; br < 2; br++) {
    const float* yy = br ? y1 : y0;
    const float* lg = br ? ln21g : ln20g;
    const float* lb = br ? ln21b : ln20b;
    const short* wk = br ? wt_cakv1 : wt_cakv0;
    const float* bk = br ? b_cakv1 : b_cakv0;
    ln_kernel<<<MKV, 256, 0, stream>>>(yy, lg, lb, bufD);
    gemm256<0><<<128, 512, 0, stream>>>(bufD, wk, bk, nullptr, kv_ca, MKV, 1024, 512, 512);
    colsum_kernel<<<256, 256, 0, stream>>>(kv_ca, ksum + (size_t)br * 2048, TBD, 1024);
    ctx_kernel<<<256, 256, 0, stream>>>(kv_ca, kv_ca + 512,
                                        ctxb + (size_t)br * 32 * 4096, TBD, 8, 1024);
  }
  qctx_kernel<<<32 * (TQD / 128), 256, 0, stream>>>(q_ca, ctxb, ksum, bufD, TQD, 2, 512);
  gemm256<2><<<128, 512, 0, stream>>>(bufD, wt_cap, capb, x, xout, MQ, 512, 512, 0);

  // ---- MLP 1 ----
  ln_kernel<<<MQ, 256, 0, stream>>>(xout, ln3g, ln3b, xn);
  gemm256<1><<<512, 512, 0, stream>>>(xn, wt_m1w1, m1b1, nullptr, h1, MQ, 2048, 512, 0);
  gemm256<2><<<128, 512, 0, stream>>>(h1, wt_m1w2, m1b2, xout, xout, MQ, 512, 2048, 0);

  // ---- self-attention (fused q|k|v projection) ----
  ln_kernel<<<MQ, 256, 0, stream>>>(xout, ln4g, ln4b, xn);
  gemm256<0><<<384, 512, 0, stream>>>(xn, wt_saqkv, b_saqkv, nullptr, qkv, MQ, 1536, 512, 1024);
  hipMemsetAsync(ksum, 0, (size_t)32 * 64 * 4, stream);
  hipMemsetAsync(ctxb, 0, (size_t)32 * 64 * 64 * 4, stream);
  colsum_kernel<<<256, 256, 0, stream>>>(qkv + 512, ksum, TQD, 1536);
  ctx_kernel<<<256, 256, 0, stream>>>(qkv + 512, qkv + 1024, ctxb, TQD, 8, 1536);
  qctx_kernel<<<32 * (TQD / 128), 256, 0, stream>>>(qkv, ctxb, ksum, bufD, TQD, 1, 1536);
  gemm256<2><<<128, 512, 0, stream>>>(bufD, wt_sap, sapb, xout, xout, MQ, 512, 512, 0);

  // ---- MLP 2 ----
  ln_kernel<<<MQ, 256, 0, stream>>>(xout, ln5g, ln5b, xn);
  gemm256<1><<<512, 512, 0, stream>>>(xn, wt_m2w1, m2b1, nullptr, h1, MQ, 2048, 512, 0);
  gemm256<2><<<128, 512, 0, stream>>>(h1, wt_m2w2, m2b2, xout, xout, MQ, 512, 2048, 0);
}

// Round 7
// 600.547 us; speedup vs baseline: 1.1946x; 1.1946x over previous
//
#include <hip/hip_runtime.h>
#include <hip/hip_bf16.h>
#include <math.h>

// Problem constants
#define NBATCH 4
#define TQD 4096
#define TBD 2048
#define CDIM 512
#define NH 8
#define HD 64
#define NINNER 2048

using short8 = __attribute__((ext_vector_type(8))) short;
using f32x4  = __attribute__((ext_vector_type(4))) float;

__device__ __forceinline__ float b2f(short s) {
  return __uint_as_float(((unsigned)(unsigned short)s) << 16);
}
__device__ __forceinline__ short f2b(float f) {
  unsigned u = __float_as_uint(f);
  return (short)((u + 0x7FFFu + ((u >> 16) & 1u)) >> 16);
}
__device__ __forceinline__ unsigned pk2(float a, float b) {
  float2 t; t.x = a; t.y = b;
  __hip_bfloat162 h = __float22bfloat162_rn(t);
  return *(unsigned*)&h;
}
__device__ __forceinline__ float gelu_fast(float x) {
  float x3 = x * x * x;
  float y2 = 1.5957691216f * (x + 0.044715f * x3);
  float e = __expf(y2);
  return x * e / (e + 1.0f);
}
__device__ __forceinline__ void gload16(const short* g, short* l) {
  __builtin_amdgcn_global_load_lds((const __attribute__((address_space(1))) void*)g,
                                   (__attribute__((address_space(3))) void*)l, 16, 0, 0);
}

// ---------------- LayerNorm (fp32 in -> bf16 out), one block per row, C=512
__launch_bounds__(256)
__global__ void ln_kernel(const float* __restrict__ x, const float* __restrict__ g,
                          const float* __restrict__ b, short* __restrict__ out)
{
  int r = blockIdx.x;
  int tid = threadIdx.x;
  float2 v = ((const float2*)(x + (size_t)r * CDIM))[tid];
  float s = v.x + v.y, s2 = v.x * v.x + v.y * v.y;
#pragma unroll
  for (int m = 1; m < 64; m <<= 1) { s += __shfl_xor(s, m); s2 += __shfl_xor(s2, m); }
  __shared__ float red[8];
  int wave = tid >> 6;
  if ((tid & 63) == 0) { red[wave] = s; red[4 + wave] = s2; }
  __syncthreads();
  s  = red[0] + red[1] + red[2] + red[3];
  s2 = red[4] + red[5] + red[6] + red[7];
  float mean = s * (1.0f / CDIM);
  float var  = s2 * (1.0f / CDIM) - mean * mean;
  float inv  = rsqrtf(var + 1e-5f);
  float2 gg = ((const float2*)g)[tid];
  float2 bb = ((const float2*)b)[tid];
  short2 o;
  o.x = f2b((v.x - mean) * inv * gg.x + bb.x);
  o.y = f2b((v.y - mean) * inv * gg.y + bb.y);
  *((short2*)(out + (size_t)r * CDIM + 2 * tid)) = o;
}

// ---------------- batched transpose+convert: W[K][N] f32 -> Wt[N][K] bf16
struct TcvtDesc {
  const float* src[14];
  short* dst[14];
  int K[14], N[14], nblk[14];
};
__launch_bounds__(256)
__global__ void tcvt_all(TcvtDesc d)
{
  int blk = blockIdx.x, wi = 0;
  while (blk >= d.nblk[wi]) { blk -= d.nblk[wi]; wi++; }
  const float* __restrict__ W = d.src[wi];
  short* __restrict__ Wt = d.dst[wi];
  int K = d.K[wi], N = d.N[wi];
  __shared__ float t[32][33];
  int nbk = K >> 5;
  int bk = blk % nbk, bn = blk / nbk;
  int cx = threadIdx.x & 31, cy = threadIdx.x >> 5;
#pragma unroll
  for (int i = 0; i < 4; i++)
    t[cy + 8 * i][cx] = W[(size_t)(bk * 32 + cy + 8 * i) * N + bn * 32 + cx];
  __syncthreads();
#pragma unroll
  for (int i = 0; i < 4; i++)
    Wt[(size_t)(bn * 32 + cy + 8 * i) * K + bk * 32 + cx] = f2b(t[cx][cy + 8 * i]);
}

#define VMW(n) asm volatile("s_waitcnt vmcnt(" #n ")" ::: "memory");

// ================= 256x256 8-phase GEMM (round-6 proven; BK=64, 8 waves) ====
// EPI: 0 = bf16 + softmax per 64-chunk where col<smLimit (+fused k-colsum
// when ksumP!=null and wave chunk in [csBase,csBase+512)); 1 = gelu bf16;
// 2 = residual-add fp32.
template<int EPI>
__launch_bounds__(512, 2)
__global__ void gemm256(const short* __restrict__ A, const short* __restrict__ Bt,
                        const float* __restrict__ bias, const float* __restrict__ resid,
                        void* __restrict__ outp, int M, int N, int K, int smLimit,
                        float* __restrict__ ksumP, int csBase, int Trows)
{
  __shared__ short As[2 * 16384];   // [buf][half(row>>7)][128][64], slot^(row&7)
  __shared__ short Bs[2 * 16384];   // [buf][kk][256][32],  slot^((row>>1)&3)
  int tid = threadIdx.x, lane = tid & 63, wave = tid >> 6;
  int l15 = lane & 15, g = lane >> 4;
  int wr = wave >> 2, wn = wave & 3;
  int nbn = N >> 8;
  int per = gridDim.x >> 3;
  int wg = (blockIdx.x & 7) * per + (blockIdx.x >> 3);
  int bm = wg / nbn, bn = wg % nbn;
  f32x4 acc[8][4] = {};

  int asl = ((lane & 7) ^ (lane >> 3)) * 8;
  int bsl = ((lane & 3) ^ ((lane >> 3) & 3)) * 8;
  const short* gA0 = A  + (size_t)(bm * 256 + wave * 16 + (lane >> 3)) * K + asl;
  const short* gB0 = Bt + (size_t)(bn * 256 + wave * 32 + (lane >> 2)) * K + bsl;
  const size_t a1off = (size_t)8 * K;
  const size_t b1off = (size_t)16 * K;
  const size_t ah1   = (size_t)128 * K;
  short* lA = As + wave * 1024;
  short* lB = Bs + wave * 1024;

  int asw0 = (g ^ (l15 & 7)) * 8;
  int asw1 = ((4 + g) ^ (l15 & 7)) * 8;
  const short* raB = As + wr * 8192 + l15 * 64;
  const short* rbB = Bs + (wn * 64 + l15) * 32 + (g ^ ((l15 >> 1) & 3)) * 8;

  short8 af[4], bfr[8];
  int NT = K >> 6, NIT = NT >> 1;

#define STGA(T, h) { \
    const short* s_ = gA0 + (h) * ah1 + (size_t)(T) * 64; \
    short* d_ = lA + ((T) & 1) * 16384 + (h) * 8192; \
    gload16(s_, d_); gload16(s_ + a1off, d_ + 512); }
#define STGB(T, kk) { \
    const short* s_ = gB0 + (size_t)(T) * 64 + (kk) * 32; \
    short* d_ = lB + ((T) & 1) * 16384 + (kk) * 8192; \
    gload16(s_, d_); gload16(s_ + b1off, d_ + 512); }
#define RDB(T) { \
    const short* bp = rbB + ((T) & 1) * 16384; \
    bfr[0] = *(const short8*)(bp);               bfr[1] = *(const short8*)(bp + 512); \
    bfr[2] = *(const short8*)(bp + 1024);        bfr[3] = *(const short8*)(bp + 1536); \
    bfr[4] = *(const short8*)(bp + 8192);        bfr[5] = *(const short8*)(bp + 8192 + 512); \
    bfr[6] = *(const short8*)(bp + 8192 + 1024); bfr[7] = *(const short8*)(bp + 8192 + 1536); }
#define RDA(T, q) { \
    const short* ap = raB + ((T) & 1) * 16384 + (q) * 2048; \
    af[0] = *(const short8*)(ap + asw0); af[1] = *(const short8*)(ap + 1024 + asw0); \
    af[2] = *(const short8*)(ap + asw1); af[3] = *(const short8*)(ap + 1024 + asw1); }
#define MFMAQ(q) { \
    __builtin_amdgcn_s_setprio(1); \
    _Pragma("unroll") for (int n = 0; n < 4; n++) { \
      acc[2*(q)][n]   = __builtin_amdgcn_mfma_f32_16x16x32_bf16(bfr[n], af[0], acc[2*(q)][n], 0, 0, 0); \
      acc[2*(q)+1][n] = __builtin_amdgcn_mfma_f32_16x16x32_bf16(bfr[n], af[1], acc[2*(q)+1][n], 0, 0, 0); } \
    _Pragma("unroll") for (int n = 0; n < 4; n++) { \
      acc[2*(q)][n]   = __builtin_amdgcn_mfma_f32_16x16x32_bf16(bfr[4+n], af[2], acc[2*(q)][n], 0, 0, 0); \
      acc[2*(q)+1][n] = __builtin_amdgcn_mfma_f32_16x16x32_bf16(bfr[4+n], af[3], acc[2*(q)+1][n], 0, 0, 0); } \
    __builtin_amdgcn_s_setprio(0); }
#define BARX  { __builtin_amdgcn_s_barrier(); __builtin_amdgcn_sched_barrier(0); }
#define BAR2  { __builtin_amdgcn_s_barrier(); }

  STGB(0, 0); STGB(0, 1); STGA(0, 0); STGA(0, 1); STGB(1, 0); STGB(1, 1);
  VMW(4);
  BAR2;

  for (int t = 0; t < NIT - 1; ++t) {
    int E = 2 * t, O = 2 * t + 1;
    RDB(E); RDA(E, 0); STGA(O, 0);     BARX; MFMAQ(0); BAR2;
    RDA(E, 1);         STGA(O, 1);     BARX; MFMAQ(1); BAR2;
    RDA(E, 2);         STGB(E + 2, 0); BARX; MFMAQ(2); BAR2;
    VMW(2);
    RDA(E, 3);         STGB(E + 2, 1); BARX; MFMAQ(3); BAR2;
    RDB(O); RDA(O, 0); STGA(E + 2, 0); BARX; MFMAQ(0); BAR2;
    RDA(O, 1);         STGA(E + 2, 1); BARX; MFMAQ(1); BAR2;
    RDA(O, 2);         STGB(O + 2, 0); BARX; MFMAQ(2); BAR2;
    VMW(2);
    RDA(O, 3);         STGB(O + 2, 1); BARX; MFMAQ(3); BAR2;
  }
  {
    int E = NT - 2, O = NT - 1;
    RDB(E); RDA(E, 0); STGA(O, 0); BARX; MFMAQ(0); BAR2;
    RDA(E, 1);         STGA(O, 1); BARX; MFMAQ(1); BAR2;
    RDA(E, 2);                     BARX; MFMAQ(2); BAR2;
    VMW(0);
    RDA(E, 3);                     BARX; MFMAQ(3); BAR2;
    RDB(O); RDA(O, 0);             BARX; MFMAQ(0); BAR2;
    RDA(O, 1);                     BARX; MFMAQ(1); BAR2;
    RDA(O, 2);                     BARX; MFMAQ(2); BAR2;
    RDA(O, 3);                     BARX; MFMAQ(3);
  }
#undef STGA
#undef STGB
#undef RDB
#undef RDA
#undef MFMAQ
#undef BARX
#undef BAR2

  int row0 = bm * 256 + wr * 128, col0 = bn * 256 + wn * 64;
#pragma unroll
  for (int n = 0; n < 4; n++) {
    f32x4 bz = *(const f32x4*)(bias + col0 + n * 16 + g * 4);
#pragma unroll
    for (int m = 0; m < 8; m++)
#pragma unroll
      for (int r = 0; r < 4; r++) acc[m][n][r] += bz[r];
  }
  if (EPI == 0 && col0 < smLimit) {
#pragma unroll
    for (int m = 0; m < 8; m++) {
      float mx = acc[m][0][0];
#pragma unroll
      for (int n = 0; n < 4; n++)
#pragma unroll
        for (int r = 0; r < 4; r++) mx = fmaxf(mx, acc[m][n][r]);
      mx = fmaxf(mx, __shfl_xor(mx, 16));
      mx = fmaxf(mx, __shfl_xor(mx, 32));
      float s = 0.0f;
#pragma unroll
      for (int n = 0; n < 4; n++)
#pragma unroll
        for (int r = 0; r < 4; r++) {
          float e = __expf(acc[m][n][r] - mx);
          acc[m][n][r] = e; s += e;
        }
      s += __shfl_xor(s, 16);
      s += __shfl_xor(s, 32);
      float inv = 1.0f / s;
#pragma unroll
      for (int n = 0; n < 4; n++)
#pragma unroll
        for (int r = 0; r < 4; r++) acc[m][n][r] *= inv;
    }
  }
  if (EPI == 0 && ksumP != nullptr) {
    unsigned rel = (unsigned)(col0 - csBase);
    if (rel < 512u) {
      float* kp = ksumP + ((row0 / Trows) * 8 + (int)(rel >> 6)) * 64;
#pragma unroll
      for (int n = 0; n < 4; n++) {
        f32x4 s = acc[0][n];
#pragma unroll
        for (int m = 1; m < 8; m++)
#pragma unroll
          for (int r = 0; r < 4; r++) s[r] += acc[m][n][r];
#pragma unroll
        for (int msk = 1; msk < 16; msk <<= 1)
#pragma unroll
          for (int r = 0; r < 4; r++) s[r] += __shfl_xor(s[r], msk);
        if (l15 == 0)
#pragma unroll
          for (int r = 0; r < 4; r++)
            atomicAdd(kp + n * 16 + g * 4 + r, s[r]);
      }
    }
  }
  if (EPI == 1) {
#pragma unroll
    for (int m = 0; m < 8; m++)
#pragma unroll
      for (int n = 0; n < 4; n++)
#pragma unroll
        for (int r = 0; r < 4; r++) acc[m][n][r] = gelu_fast(acc[m][n][r]);
  }
#pragma unroll
  for (int m = 0; m < 8; m++) {
    int row = row0 + m * 16 + l15;
#pragma unroll
    for (int n = 0; n < 4; n++) {
      size_t base = (size_t)row * N + col0 + n * 16 + g * 4;
      if (EPI == 2) {
        f32x4 rv = *(const f32x4*)(resid + base);
        f32x4 o;
#pragma unroll
        for (int r = 0; r < 4; r++) o[r] = rv[r] + acc[m][n][r];
        *(f32x4*)((float*)outp + base) = o;
      } else {
        uint2 u;
        u.x = pk2(acc[m][n][0], acc[m][n][1]);
        u.y = pk2(acc[m][n][2], acc[m][n][3]);
        *(uint2*)((unsigned short*)outp + base) = u;
      }
    }
  }
}

// ================= 128x256 4-phase GEMM (BK=64, 8 waves, A quad-buffered) ===
// Grid = (M/128)*(N/256) -> 256 blocks for the N<=1024 shapes (full chip).
// A-LDS [4buf][128][64] swz slot^(row&7); B-LDS [2buf][kk][256][32] swz
// slot^((row>>1)&3). Iter t (tiles E=2t, O=2t+1) stages tiles E+2/O+2:
//   ph0: rd{B(E),A(E,q0)}  STGA(E+2)            bar MFMA(q0) bar
//   ph1: VMW(2) rdA(E,q1)  STGB(E+2,0)+(E+2,1)  bar MFMA(q1) bar
//   ph2: rd{B(O),A(O,q0)}  STGA(O+2)            bar MFMA(q0) bar
//   ph3: VMW(2) rdA(O,q1)  STGB(O+2,0)+(O+2,1)  bar MFMA(q1) bar
// Outstanding trace (steady): enter ph0 = 6 {A(O)2,B(O)4}; ph0 +2 = 8;
// ph1 VMW(2) drains tile O (6) -> publish for ph2 reads (after ph1 barrier);
// ph1 +4 = 6; ph2 +2 = 8; ph3 VMW(2) drains E+2 (6) -> publish for next ph0;
// ph3 +4 = 6. Cover >= 2 phases per load. WAR: B(E+2) writes buf E&1 one
// barrier after ph0's RDB(E) (reads landed in regs by ph0 lgkmcnt); A(T+2)
// buffers disjoint from live reads (4 bufs, stride 2). Peel: VMW(0) at ph1.
template<int EPI>
__launch_bounds__(512, 2)
__global__ void gemm128(const short* __restrict__ A, const short* __restrict__ Bt,
                        const float* __restrict__ bias, const float* __restrict__ resid,
                        void* __restrict__ outp, int M, int N, int K, int smLimit,
                        float* __restrict__ ksumP, int csBase, int Trows)
{
  __shared__ short As[4 * 8192];
  __shared__ short Bs[2 * 16384];
  int tid = threadIdx.x, lane = tid & 63, wave = tid >> 6;
  int l15 = lane & 15, g = lane >> 4;
  int wr = wave >> 2, wn = wave & 3;
  int nbn = N >> 8;
  int per = gridDim.x >> 3;
  int wg = (blockIdx.x & 7) * per + (blockIdx.x >> 3);
  int bm = wg / nbn, bn = wg % nbn;
  f32x4 acc[4][4] = {};

  int asl = ((lane & 7) ^ (lane >> 3)) * 8;
  int bsl = ((lane & 3) ^ ((lane >> 3) & 3)) * 8;
  const short* gA0 = A  + (size_t)(bm * 128 + wave * 16 + (lane >> 3)) * K + asl;
  const short* gB0 = Bt + (size_t)(bn * 256 + wave * 32 + (lane >> 2)) * K + bsl;
  const size_t a1off = (size_t)8 * K;
  const size_t b1off = (size_t)16 * K;
  short* lA = As + wave * 1024;
  short* lB = Bs + wave * 1024;

  int asw0 = (g ^ (l15 & 7)) * 8;
  int asw1 = ((4 + g) ^ (l15 & 7)) * 8;
  const short* raB = As + wr * 4096 + l15 * 64;
  const short* rbB = Bs + (wn * 64 + l15) * 32 + (g ^ ((l15 >> 1) & 3)) * 8;

  short8 af[4], bfr[8];
  int NT = K >> 6, NIT = NT >> 1;

#define STGA1(T) { \
    const short* s_ = gA0 + (size_t)(T) * 64; \
    short* d_ = lA + ((T) & 3) * 8192; \
    gload16(s_, d_); gload16(s_ + a1off, d_ + 512); }
#define STGB1(T, kk) { \
    const short* s_ = gB0 + (size_t)(T) * 64 + (kk) * 32; \
    short* d_ = lB + ((T) & 1) * 16384 + (kk) * 8192; \
    gload16(s_, d_); gload16(s_ + b1off, d_ + 512); }
#define RDB1(T) { \
    const short* bp = rbB + ((T) & 1) * 16384; \
    bfr[0] = *(const short8*)(bp);               bfr[1] = *(const short8*)(bp + 512); \
    bfr[2] = *(const short8*)(bp + 1024);        bfr[3] = *(const short8*)(bp + 1536); \
    bfr[4] = *(const short8*)(bp + 8192);        bfr[5] = *(const short8*)(bp + 8192 + 512); \
    bfr[6] = *(const short8*)(bp + 8192 + 1024); bfr[7] = *(const short8*)(bp + 8192 + 1536); }
#define RDA1(T, q) { \
    const short* ap = raB + ((T) & 3) * 8192 + (q) * 2048; \
    af[0] = *(const short8*)(ap + asw0); af[1] = *(const short8*)(ap + 1024 + asw0); \
    af[2] = *(const short8*)(ap + asw1); af[3] = *(const short8*)(ap + 1024 + asw1); }
#define MFMAQ1(q) { \
    __builtin_amdgcn_s_setprio(1); \
    _Pragma("unroll") for (int n = 0; n < 4; n++) { \
      acc[2*(q)][n]   = __builtin_amdgcn_mfma_f32_16x16x32_bf16(bfr[n], af[0], acc[2*(q)][n], 0, 0, 0); \
      acc[2*(q)+1][n] = __builtin_amdgcn_mfma_f32_16x16x32_bf16(bfr[n], af[1], acc[2*(q)+1][n], 0, 0, 0); } \
    _Pragma("unroll") for (int n = 0; n < 4; n++) { \
      acc[2*(q)][n]   = __builtin_amdgcn_mfma_f32_16x16x32_bf16(bfr[4+n], af[2], acc[2*(q)][n], 0, 0, 0); \
      acc[2*(q)+1][n] = __builtin_amdgcn_mfma_f32_16x16x32_bf16(bfr[4+n], af[3], acc[2*(q)+1][n], 0, 0, 0); } \
    __builtin_amdgcn_s_setprio(0); }
#define BARX1 { __builtin_amdgcn_s_barrier(); __builtin_amdgcn_sched_barrier(0); }
#define BAR21 { __builtin_amdgcn_s_barrier(); }

  // prologue: T0 {A,B0,B1}, T1 {A,B0,B1}; publish T0 (drain its 6)
  STGA1(0); STGB1(0, 0); STGB1(0, 1);
  STGA1(1); STGB1(1, 0); STGB1(1, 1);
  VMW(6);
  BAR21;

  for (int t = 0; t < NIT - 1; ++t) {
    int E = 2 * t, O = 2 * t + 1;
    RDB1(E); RDA1(E, 0); STGA1(E + 2);                  BARX1; MFMAQ1(0); BAR21;
    VMW(2);
    RDA1(E, 1);          STGB1(E + 2, 0); STGB1(E + 2, 1); BARX1; MFMAQ1(1); BAR21;
    RDB1(O); RDA1(O, 0); STGA1(O + 2);                  BARX1; MFMAQ1(0); BAR21;
    VMW(2);
    RDA1(O, 1);          STGB1(O + 2, 0); STGB1(O + 2, 1); BARX1; MFMAQ1(1); BAR21;
  }
  {
    int E = NT - 2, O = NT - 1;
    RDB1(E); RDA1(E, 0); BARX1; MFMAQ1(0); BAR21;
    VMW(0);
    RDA1(E, 1);          BARX1; MFMAQ1(1); BAR21;
    RDB1(O); RDA1(O, 0); BARX1; MFMAQ1(0); BAR21;
    RDA1(O, 1);          BARX1; MFMAQ1(1);
  }
#undef STGA1
#undef STGB1
#undef RDB1
#undef RDA1
#undef MFMAQ1
#undef BARX1
#undef BAR21

  int row0 = bm * 128 + wr * 64, col0 = bn * 256 + wn * 64;
#pragma unroll
  for (int n = 0; n < 4; n++) {
    f32x4 bz = *(const f32x4*)(bias + col0 + n * 16 + g * 4);
#pragma unroll
    for (int m = 0; m < 4; m++)
#pragma unroll
      for (int r = 0; r < 4; r++) acc[m][n][r] += bz[r];
  }
  if (EPI == 0 && col0 < smLimit) {
#pragma unroll
    for (int m = 0; m < 4; m++) {
      float mx = acc[m][0][0];
#pragma unroll
      for (int n = 0; n < 4; n++)
#pragma unroll
        for (int r = 0; r < 4; r++) mx = fmaxf(mx, acc[m][n][r]);
      mx = fmaxf(mx, __shfl_xor(mx, 16));
      mx = fmaxf(mx, __shfl_xor(mx, 32));
      float s = 0.0f;
#pragma unroll
      for (int n = 0; n < 4; n++)
#pragma unroll
        for (int r = 0; r < 4; r++) {
          float e = __expf(acc[m][n][r] - mx);
          acc[m][n][r] = e; s += e;
        }
      s += __shfl_xor(s, 16);
      s += __shfl_xor(s, 32);
      float inv = 1.0f / s;
#pragma unroll
      for (int n = 0; n < 4; n++)
#pragma unroll
        for (int r = 0; r < 4; r++) acc[m][n][r] *= inv;
    }
  }
  if (EPI == 0 && ksumP != nullptr) {
    unsigned rel = (unsigned)(col0 - csBase);
    if (rel < 512u) {
      float* kp = ksumP + ((row0 / Trows) * 8 + (int)(rel >> 6)) * 64;
#pragma unroll
      for (int n = 0; n < 4; n++) {
        f32x4 s = acc[0][n];
#pragma unroll
        for (int m = 1; m < 4; m++)
#pragma unroll
          for (int r = 0; r < 4; r++) s[r] += acc[m][n][r];
#pragma unroll
        for (int msk = 1; msk < 16; msk <<= 1)
#pragma unroll
          for (int r = 0; r < 4; r++) s[r] += __shfl_xor(s[r], msk);
        if (l15 == 0)
#pragma unroll
          for (int r = 0; r < 4; r++)
            atomicAdd(kp + n * 16 + g * 4 + r, s[r]);
      }
    }
  }
  if (EPI == 1) {
#pragma unroll
    for (int m = 0; m < 4; m++)
#pragma unroll
      for (int n = 0; n < 4; n++)
#pragma unroll
        for (int r = 0; r < 4; r++) acc[m][n][r] = gelu_fast(acc[m][n][r]);
  }
#pragma unroll
  for (int m = 0; m < 4; m++) {
    int row = row0 + m * 16 + l15;
#pragma unroll
    for (int n = 0; n < 4; n++) {
      size_t base = (size_t)row * N + col0 + n * 16 + g * 4;
      if (EPI == 2) {
        f32x4 rv = *(const f32x4*)(resid + base);
        f32x4 o;
#pragma unroll
        for (int r = 0; r < 4; r++) o[r] = rv[r] + acc[m][n][r];
        *(f32x4*)((float*)outp + base) = o;
      } else {
        uint2 u;
        u.x = pk2(acc[m][n][0], acc[m][n][1]);
        u.y = pk2(acc[m][n][2], acc[m][n][3]);
        *(uint2*)((unsigned short*)outp + base) = u;
      }
    }
  }
}

// ---------------- ctx += k^T v per (b,h); grid = 32*parts, atomics into zeroed ctx
#define LDC 40
__launch_bounds__(256)
__global__ void ctx_kernel(const short* __restrict__ k, const short* __restrict__ v,
                           float* __restrict__ ctx, int T, int parts, int SD)
{
  __shared__ short kT[4][64 * LDC];
  __shared__ short vT[4][64 * LDC];
  int bh = blockIdx.x & 31, part = blockIdx.x >> 5;
  int b = bh >> 3, h = bh & 7;
  int tid = threadIdx.x, lane = tid & 63, wave = tid >> 6;
  int l15 = lane & 15, g = lane >> 4;
  int tlen = T / (4 * parts);
  int tbeg = (part * 4 + wave) * tlen;
  f32x4 acc[4][4] = {};
  short* myK = kT[wave];
  short* myV = vT[wave];
  for (int t0 = tbeg; t0 < tbeg + tlen; t0 += 32) {
#pragma unroll
    for (int j = 0; j < 4; j++) {
      int c = lane + j * 64;
      int r = c >> 3, d0 = (c & 7) * 8;
      short8 kv = *(const short8*)(k + (size_t)(b * T + t0 + r) * SD + h * 64 + d0);
      short8 vv = *(const short8*)(v + (size_t)(b * T + t0 + r) * SD + h * 64 + d0);
#pragma unroll
      for (int i = 0; i < 8; i++) {
        myK[(d0 + i) * LDC + r] = kv[i];
        myV[(d0 + i) * LDC + r] = vv[i];
      }
    }
    __syncthreads();
    short8 af[4], bfr[4];
#pragma unroll
    for (int m = 0; m < 4; m++) af[m]  = *(const short8*)(myK + (m * 16 + l15) * LDC + g * 8);
#pragma unroll
    for (int n = 0; n < 4; n++) bfr[n] = *(const short8*)(myV + (n * 16 + l15) * LDC + g * 8);
#pragma unroll
    for (int m = 0; m < 4; m++)
#pragma unroll
      for (int n = 0; n < 4; n++)
        acc[m][n] = __builtin_amdgcn_mfma_f32_16x16x32_bf16(af[m], bfr[n], acc[m][n], 0, 0, 0);
    __syncthreads();
  }
  float* cp = ctx + (size_t)bh * 64 * 64;
#pragma unroll
  for (int m = 0; m < 4; m++)
#pragma unroll
    for (int n = 0; n < 4; n++)
#pragma unroll
      for (int r = 0; r < 4; r++)
        atomicAdd(cp + (m * 16 + g * 4 + r) * 64 + (n * 16 + l15), acc[m][n][r]);
}

// ---------------- out[t,:] = q[t,:] + sum_br dinv(t) * (q[t,:] @ ctx[br])
#define LQ 72
__launch_bounds__(256)
__global__ void qctx_kernel(const short* __restrict__ q,
                            const float* __restrict__ ctx,   // [nb][32][64][64]
                            const float* __restrict__ ksum,  // [nb][32][64]
                            short* __restrict__ outp, int T, int nb, int SD)
{
  __shared__ short qs[128 * LQ];
  __shared__ short cT[2][64 * LQ];
  __shared__ float dls[2][128];
  int ntb = T >> 7;
  int bh = blockIdx.x / ntb, tq = blockIdx.x % ntb;
  int b = bh >> 3, h = bh & 7;
  int tid = threadIdx.x, lane = tid & 63, wave = tid >> 6;
  int l15 = lane & 15, g = lane >> 4;
  size_t qbase = (size_t)(b * T + tq * 128) * SD + h * 64;
  size_t obase = (size_t)(b * T + tq * 128) * CDIM + h * 64;

#pragma unroll
  for (int j = 0; j < 4; j++) {
    int c = tid + j * 256;
    int r = c >> 3, d0 = (c & 7) * 8;
    *(short8*)(qs + r * LQ + d0) = *(const short8*)(q + qbase + (size_t)r * SD + d0);
  }
  for (int br = 0; br < nb; br++) {
    const float* cp = ctx + ((size_t)br * 32 + bh) * 4096;
#pragma unroll
    for (int j = 0; j < 16; j++) {
      int e2 = tid + j * 256;
      int dd = e2 >> 6, ee = e2 & 63;
      cT[br][ee * LQ + dd] = f2b(cp[e2]);
    }
  }
  __syncthreads();

  int r0 = wave * 32;
  for (int br = 0; br < nb; br++) {
    int row = r0 + (lane >> 1);
    int dbase = (lane & 1) * 32;
    const float* kp = ksum + ((size_t)br * 32 + bh) * 64 + dbase;
    float s = 0.0f;
#pragma unroll
    for (int d = 0; d < 32; d++)
      s += b2f(qs[row * LQ + dbase + d]) * kp[d];
    s += __shfl_xor(s, 1);
    if (!(lane & 1)) dls[br][row] = 1.0f / fmaxf(s, 1e-9f);
  }

  short8 af[2][2];
#pragma unroll
  for (int m = 0; m < 2; m++)
#pragma unroll
    for (int kk = 0; kk < 2; kk++)
      af[m][kk] = *(const short8*)(qs + (r0 + m * 16 + l15) * LQ + kk * 32 + g * 8);

  float ofin[2][4][4];
#pragma unroll
  for (int m = 0; m < 2; m++)
#pragma unroll
    for (int n = 0; n < 4; n++)
#pragma unroll
      for (int r = 0; r < 4; r++)
        ofin[m][n][r] = b2f(qs[(r0 + m * 16 + g * 4 + r) * LQ + n * 16 + l15]);

  for (int br = 0; br < nb; br++) {
    f32x4 acc[2][4] = {};
#pragma unroll
    for (int kk = 0; kk < 2; kk++) {
      short8 bfr[4];
#pragma unroll
      for (int n = 0; n < 4; n++)
        bfr[n] = *(const short8*)(cT[br] + (n * 16 + l15) * LQ + kk * 32 + g * 8);
#pragma unroll
      for (int m = 0; m < 2; m++)
#pragma unroll
        for (int n = 0; n < 4; n++)
          acc[m][n] = __builtin_amdgcn_mfma_f32_16x16x32_bf16(af[m][kk], bfr[n], acc[m][n], 0, 0, 0);
    }
#pragma unroll
    for (int m = 0; m < 2; m++)
#pragma unroll
      for (int n = 0; n < 4; n++)
#pragma unroll
        for (int r = 0; r < 4; r++)
          ofin[m][n][r] += dls[br][r0 + m * 16 + g * 4 + r] * acc[m][n][r];
  }

#pragma unroll
  for (int m = 0; m < 2; m++)
#pragma unroll
    for (int n = 0; n < 4; n++)
#pragma unroll
      for (int r = 0; r < 4; r++) {
        int row = r0 + m * 16 + g * 4 + r;
        int col = n * 16 + l15;
        outp[obase + (size_t)row * CDIM + col] = f2b(ofin[m][n][r]);
      }
}

extern "C" void kernel_launch(void* const* d_in, const int* in_sizes, int n_in,
                              void* d_out, int out_size, void* d_ws, size_t ws_size,
                              hipStream_t stream)
{
  (void)in_sizes; (void)n_in; (void)out_size; (void)ws_size;
  const float* x     = (const float*)d_in[0];
  const float* y0    = (const float*)d_in[1];
  const float* y1    = (const float*)d_in[2];
  const float* ln1g  = (const float*)d_in[3];
  const float* ln1b  = (const float*)d_in[4];
  const float* ln20g = (const float*)d_in[5];
  const float* ln20b = (const float*)d_in[6];
  const float* ln21g = (const float*)d_in[7];
  const float* ln21b = (const float*)d_in[8];
  const float* ln3g  = (const float*)d_in[9];
  const float* ln3b  = (const float*)d_in[10];
  const float* ln4g  = (const float*)d_in[11];
  const float* ln4b  = (const float*)d_in[12];
  const float* ln5g  = (const float*)d_in[13];
  const float* ln5b  = (const float*)d_in[14];
  const float* caqw  = (const float*)d_in[15];
  const float* caqb  = (const float*)d_in[16];
  const float* cak0w = (const float*)d_in[17];
  const float* cak0b = (const float*)d_in[18];
  const float* cav0w = (const float*)d_in[19];
  const float* cav0b = (const float*)d_in[20];
  const float* cak1w = (const float*)d_in[21];
  const float* cak1b = (const float*)d_in[22];
  const float* cav1w = (const float*)d_in[23];
  const float* cav1b = (const float*)d_in[24];
  const float* capw  = (const float*)d_in[25];
  const float* capb  = (const float*)d_in[26];
  const float* saqw  = (const float*)d_in[27];
  const float* saqb  = (const float*)d_in[28];
  const float* sakw  = (const float*)d_in[29];
  const float* sakb  = (const float*)d_in[30];
  const float* savw  = (const float*)d_in[31];
  const float* savb  = (const float*)d_in[32];
  const float* sapw  = (const float*)d_in[33];
  const float* sapb  = (const float*)d_in[34];
  const float* m1w1  = (const float*)d_in[35];
  const float* m1b1  = (const float*)d_in[36];
  const float* m1w2  = (const float*)d_in[37];
  const float* m1b2  = (const float*)d_in[38];
  const float* m2w1  = (const float*)d_in[39];
  const float* m2b1  = (const float*)d_in[40];
  const float* m2w2  = (const float*)d_in[41];
  const float* m2b2  = (const float*)d_in[42];
  float* xout = (float*)d_out;

  char* p = (char*)d_ws;
  size_t off = 0;
  auto take = [&](size_t bytes) {
    char* r = p + off;
    off += (bytes + 255) & ~(size_t)255;
    return r;
  };
  const size_t W512 = (size_t)512 * 512 * 2;
  const size_t WMLP = (size_t)2048 * 512 * 2;
  short* wt_caq   = (short*)take(W512);
  short* wt_cakv0 = (short*)take(2 * W512);       // [k;v] 1024x512
  short* wt_cakv1 = (short*)take(2 * W512);
  short* wt_cap   = (short*)take(W512);
  short* wt_saqkv = (short*)take(3 * W512);       // [q;k;v] 1536x512
  short* wt_sap   = (short*)take(W512);
  short* wt_m1w1  = (short*)take(WMLP);
  short* wt_m1w2  = (short*)take(WMLP);
  short* wt_m2w1  = (short*)take(WMLP);
  short* wt_m2w2  = (short*)take(WMLP);
  float* b_saqkv  = (float*)take(1536 * 4);
  float* b_cakv0  = (float*)take(1024 * 4);
  float* b_cakv1  = (float*)take(1024 * 4);
  short* xn   = (short*)take((size_t)16384 * 512 * 2);
  short* bufD = (short*)take((size_t)16384 * 512 * 2);
  short* big  = (short*)take((size_t)16384 * 1536 * 2);   // CA: q@0, kv@+8M shorts; SA: qkv
  short* h1   = (short*)take((size_t)16384 * 2048 * 2);
  float* ksum = (float*)take((size_t)2 * 32 * 64 * 4);
  float* ctxb = (float*)take((size_t)2 * 32 * 64 * 64 * 4);

  short* q_ca  = big;
  short* kv_ca = big + (size_t)8 * 1024 * 1024;
  short* qkv   = big;

  const int MQ  = NBATCH * TQD;   // 16384
  const int MKV = NBATCH * TBD;   // 8192

  // ---- weight transpose+convert (single batched launch) ----
  {
    TcvtDesc d;
    const float* srcs[14] = {caqw, cak0w, cav0w, cak1w, cav1w, capw,
                             saqw, sakw, savw, sapw, m1w1, m1w2, m2w1, m2w2};
    short* dsts[14] = {wt_caq, wt_cakv0, wt_cakv0 + 512 * 512,
                       wt_cakv1, wt_cakv1 + 512 * 512, wt_cap,
                       wt_saqkv, wt_saqkv + 512 * 512, wt_saqkv + 2 * 512 * 512, wt_sap,
                       wt_m1w1, wt_m1w2, wt_m2w1, wt_m2w2};
    int Ks[14] = {512,512,512,512,512,512,512,512,512,512, 512,2048,512,2048};
    int Ns[14] = {512,512,512,512,512,512,512,512,512,512, 2048,512,2048,512};
    int total = 0;
    for (int i = 0; i < 14; i++) {
      d.src[i] = srcs[i]; d.dst[i] = dsts[i]; d.K[i] = Ks[i]; d.N[i] = Ns[i];
      d.nblk[i] = (Ks[i] >> 5) * (Ns[i] >> 5);
      total += d.nblk[i];
    }
    tcvt_all<<<total, 256, 0, stream>>>(d);
  }
  // ---- bias concats ----
  hipMemcpyAsync(b_saqkv,        saqb,  512 * 4, hipMemcpyDeviceToDevice, stream);
  hipMemcpyAsync(b_saqkv + 512,  sakb,  512 * 4, hipMemcpyDeviceToDevice, stream);
  hipMemcpyAsync(b_saqkv + 1024, savb,  512 * 4, hipMemcpyDeviceToDevice, stream);
  hipMemcpyAsync(b_cakv0,        cak0b, 512 * 4, hipMemcpyDeviceToDevice, stream);
  hipMemcpyAsync(b_cakv0 + 512,  cav0b, 512 * 4, hipMemcpyDeviceToDevice, stream);
  hipMemcpyAsync(b_cakv1,        cak1b, 512 * 4, hipMemcpyDeviceToDevice, stream);
  hipMemcpyAsync(b_cakv1 + 512,  cav1b, 512 * 4, hipMemcpyDeviceToDevice, stream);

  // ---- cross-attention ----
  ln_kernel<<<MQ, 256, 0, stream>>>(x, ln1g, ln1b, xn);
  hipMemsetAsync(ksum, 0, (size_t)2 * 32 * 64 * 4, stream);
  hipMemsetAsync(ctxb, 0, (size_t)2 * 32 * 64 * 64 * 4, stream);
  gemm128<0><<<256, 512, 0, stream>>>(xn, wt_caq, caqb, nullptr, q_ca,
                                      MQ, 512, 512, 512, nullptr, 0, 0);
  for (int br = 0; br < 2; br++) {
    const float* yy = br ? y1 : y0;
    const float* lg = br ? ln21g : ln20g;
    const float* lb = br ? ln21b : ln20b;
    const short* wk = br ? wt_cakv1 : wt_cakv0;
    const float* bk = br ? b_cakv1 : b_cakv0;
    ln_kernel<<<MKV, 256, 0, stream>>>(yy, lg, lb, bufD);
    gemm128<0><<<256, 512, 0, stream>>>(bufD, wk, bk, nullptr, kv_ca,
                                        MKV, 1024, 512, 512,
                                        ksum + (size_t)br * 2048, 0, TBD);
    ctx_kernel<<<256, 256, 0, stream>>>(kv_ca, kv_ca + 512,
                                        ctxb + (size_t)br * 32 * 4096, TBD, 8, 1024);
  }
  qctx_kernel<<<32 * (TQD / 128), 256, 0, stream>>>(q_ca, ctxb, ksum, bufD, TQD, 2, 512);
  gemm128<2><<<256, 512, 0, stream>>>(bufD, wt_cap, capb, x, xout,
                                      MQ, 512, 512, 0, nullptr, 0, 0);

  // ---- MLP 1 ----
  ln_kernel<<<MQ, 256, 0, stream>>>(xout, ln3g, ln3b, xn);
  gemm256<1><<<512, 512, 0, stream>>>(xn, wt_m1w1, m1b1, nullptr, h1,
                                      MQ, 2048, 512, 0, nullptr, 0, 0);
  gemm128<2><<<256, 512, 0, stream>>>(h1, wt_m1w2, m1b2, xout, xout,
                                      MQ, 512, 2048, 0, nullptr, 0, 0);

  // ---- self-attention (fused q|k|v projection; k-colsum fused) ----
  ln_kernel<<<MQ, 256, 0, stream>>>(xout, ln4g, ln4b, xn);
  hipMemsetAsync(ksum, 0, (size_t)32 * 64 * 4, stream);
  hipMemsetAsync(ctxb, 0, (size_t)32 * 64 * 64 * 4, stream);
  gemm256<0><<<384, 512, 0, stream>>>(xn, wt_saqkv, b_saqkv, nullptr, qkv,
                                      MQ, 1536, 512, 1024, ksum, 512, TQD);
  ctx_kernel<<<256, 256, 0, stream>>>(qkv + 512, qkv + 1024, ctxb, TQD, 8, 1536);
  qctx_kernel<<<32 * (TQD / 128), 256, 0, stream>>>(qkv, ctxb, ksum, bufD, TQD, 1, 1536);
  gemm128<2><<<256, 512, 0, stream>>>(bufD, wt_sap, sapb, xout, xout,
                                      MQ, 512, 512, 0, nullptr, 0, 0);

  // ---- MLP 2 ----
  ln_kernel<<<MQ, 256, 0, stream>>>(xout, ln5g, ln5b, xn);
  gemm256<1><<<512, 512, 0, stream>>>(xn, wt_m2w1, m2b1, nullptr, h1,
                                      MQ, 2048, 512, 0, nullptr, 0, 0);
  gemm128<2><<<256, 512, 0, stream>>>(h1, wt_m2w2, m2b2, xout, xout,
                                      MQ, 512, 2048, 0, nullptr, 0, 0);
}

// Round 8
// 563.705 us; speedup vs baseline: 1.2727x; 1.0654x over previous
//
#include <hip/hip_runtime.h>
#include <hip/hip_bf16.h>
#include <math.h>

// Problem constants
#define NBATCH 4
#define TQD 4096
#define TBD 2048
#define CDIM 512
#define NH 8
#define HD 64
#define NINNER 2048

using short8 = __attribute__((ext_vector_type(8))) short;
using f32x4  = __attribute__((ext_vector_type(4))) float;

__device__ __forceinline__ float b2f(short s) {
  return __uint_as_float(((unsigned)(unsigned short)s) << 16);
}
__device__ __forceinline__ short f2b(float f) {
  unsigned u = __float_as_uint(f);
  return (short)((u + 0x7FFFu + ((u >> 16) & 1u)) >> 16);
}
__device__ __forceinline__ unsigned pk2(float a, float b) {
  float2 t; t.x = a; t.y = b;
  __hip_bfloat162 h = __float22bfloat162_rn(t);
  return *(unsigned*)&h;
}
__device__ __forceinline__ float gelu_fast(float x) {
  float x3 = x * x * x;
  float y2 = 1.5957691216f * (x + 0.044715f * x3);
  float e = __expf(y2);
  return x * e / (e + 1.0f);
}
__device__ __forceinline__ void gload16(const short* g, short* l) {
  __builtin_amdgcn_global_load_lds((const __attribute__((address_space(1))) void*)g,
                                   (__attribute__((address_space(3))) void*)l, 16, 0, 0);
}

// ---------------- LayerNorm (fp32 in -> bf16 out), wave-per-row, 4 rows/block
__launch_bounds__(256)
__global__ void ln_kernel(const float* __restrict__ x, const float* __restrict__ g,
                          const float* __restrict__ b, short* __restrict__ out)
{
  int row = blockIdx.x * 4 + (threadIdx.x >> 6);
  int lane = threadIdx.x & 63;
  const float4* xp = (const float4*)(x + (size_t)row * CDIM);
  float4 v0 = xp[lane], v1 = xp[lane + 64];
  float s  = v0.x + v0.y + v0.z + v0.w + v1.x + v1.y + v1.z + v1.w;
  float s2 = v0.x * v0.x + v0.y * v0.y + v0.z * v0.z + v0.w * v0.w
           + v1.x * v1.x + v1.y * v1.y + v1.z * v1.z + v1.w * v1.w;
#pragma unroll
  for (int m = 1; m < 64; m <<= 1) { s += __shfl_xor(s, m); s2 += __shfl_xor(s2, m); }
  float mean = s * (1.0f / CDIM);
  float var  = s2 * (1.0f / CDIM) - mean * mean;
  float inv  = rsqrtf(var + 1e-5f);
  float4 g0 = ((const float4*)g)[lane], g1 = ((const float4*)g)[lane + 64];
  float4 b0 = ((const float4*)b)[lane], b1 = ((const float4*)b)[lane + 64];
  uint2 o0, o1;
  o0.x = pk2((v0.x - mean) * inv * g0.x + b0.x, (v0.y - mean) * inv * g0.y + b0.y);
  o0.y = pk2((v0.z - mean) * inv * g0.z + b0.z, (v0.w - mean) * inv * g0.w + b0.w);
  o1.x = pk2((v1.x - mean) * inv * g1.x + b1.x, (v1.y - mean) * inv * g1.y + b1.y);
  o1.y = pk2((v1.z - mean) * inv * g1.z + b1.z, (v1.w - mean) * inv * g1.w + b1.w);
  uint2* op = (uint2*)(out + (size_t)row * CDIM);
  op[lane] = o0;
  op[lane + 64] = o1;
}

// ---------------- batched transpose+convert: W[K][N] f32 -> Wt[N][K] bf16
struct TcvtDesc {
  const float* src[14];
  short* dst[14];
  int K[14], N[14], nblk[14];
};
__launch_bounds__(256)
__global__ void tcvt_all(TcvtDesc d)
{
  int blk = blockIdx.x, wi = 0;
  while (blk >= d.nblk[wi]) { blk -= d.nblk[wi]; wi++; }
  const float* __restrict__ W = d.src[wi];
  short* __restrict__ Wt = d.dst[wi];
  int K = d.K[wi], N = d.N[wi];
  __shared__ float t[32][33];
  int nbk = K >> 5;
  int bk = blk % nbk, bn = blk / nbk;
  int cx = threadIdx.x & 31, cy = threadIdx.x >> 5;
#pragma unroll
  for (int i = 0; i < 4; i++)
    t[cy + 8 * i][cx] = W[(size_t)(bk * 32 + cy + 8 * i) * N + bn * 32 + cx];
  __syncthreads();
#pragma unroll
  for (int i = 0; i < 4; i++)
    Wt[(size_t)(bn * 32 + cy + 8 * i) * K + bk * 32 + cx] = f2b(t[cx][cy + 8 * i]);
}

#define VMW(n) asm volatile("s_waitcnt vmcnt(" #n ")" ::: "memory");

// ================= 128x256 GEMM, BK=32, 2 phases/K-tile, 2 blocks/CU ========
// LDS 64KB: A quad-buffered [4][128][32] (stage T+2 during T, 2-phase cover);
// B double-buffered [2][256][32] (stage T+1 during T, 1-phase cover; B =
// weights, L2-resident). Swizzle slot^=((row>>1)&3) both sides (r4-proven).
// Per tile T (steady; outstanding trace in {}):
//  ph0: RDB(T) RDA(T,q0); STGB(T+1){A(T+1),B(T+1)x2 =3}; BARX; 8 MFMA; BAR2
//  ph1: RDA(T,q1); STGA(T+2){+1=4}; VMW(1) [drains A(T+1),B(T+1)x2; keeps
//       A(T+2)]; BARX; 8 MFMA; BAR2   -> T+1 published 2 barriers before its
//       first read (ph0(T+1)).
// Cover: A(T+1) issued ph1(T-1) waited ph1(T) = 2 phases; B(T+1) 1 phase.
// WAR: STGB(T+1)->buf (T-1)&1, last read ph0(T-1), 3 barriers prior;
//      STGA(T+2)->buf (T-2)&3, last read ph1(T-2). Peel: last 2 tiles, VMW(0).
// EPI: 0 = bf16 + softmax per 64-chunk where col<smLimit (+fused k-colsum when
// ksumP!=null, cols [csBase,csBase+512)); 1 = gelu bf16; 2 = residual fp32.
template<int EPI>
__launch_bounds__(512, 4)
__global__ void gemm128(const short* __restrict__ A, const short* __restrict__ Bt,
                        const float* __restrict__ bias, const float* __restrict__ resid,
                        void* __restrict__ outp, int M, int N, int K, int smLimit,
                        float* __restrict__ ksumP, int csBase, int Trows)
{
  __shared__ short As[4 * 4096];   // 4 bufs x [128][32]
  __shared__ short Bs[2 * 8192];   // 2 bufs x [256][32]
  int tid = threadIdx.x, lane = tid & 63, wave = tid >> 6;
  int l15 = lane & 15, g = lane >> 4;
  int wr = wave >> 2, wn = wave & 3;
  int nbn = N >> 8;
  int per = gridDim.x >> 3;
  int wg = (blockIdx.x & 7) * per + (blockIdx.x >> 3);
  int bm = wg / nbn, bn = wg % nbn;
  f32x4 acc[4][4] = {};

  int srcslot = ((lane & 3) ^ ((lane >> 3) & 3)) * 8;
  const short* gA0 = A  + (size_t)(bm * 128 + wave * 16 + (lane >> 2)) * K + srcslot;
  const short* gB0 = Bt + (size_t)(bn * 256 + wave * 16 + (lane >> 2)) * K + srcslot;
  const short* gB1 = gB0 + (size_t)128 * K;
  short* lA = As + wave * 512;
  short* lB = Bs + wave * 512;

  int rsw = (g ^ ((l15 >> 1) & 3)) * 8;
  const short* raB = As + (wr * 64 + l15) * 32 + rsw;
  const short* rbB = Bs + (wn * 64 + l15) * 32 + rsw;

  short8 af[2], bfr[4];
  int NT = K >> 5;

#define STGA1(T) gload16(gA0 + (size_t)(T) * 32, lA + ((T) & 3) * 4096);
#define STGB1(T) { \
    gload16(gB0 + (size_t)(T) * 32, lB + ((T) & 1) * 8192); \
    gload16(gB1 + (size_t)(T) * 32, lB + ((T) & 1) * 8192 + 4096); }
#define RDB1(T) { \
    const short* bp = rbB + ((T) & 1) * 8192; \
    bfr[0] = *(const short8*)(bp);        bfr[1] = *(const short8*)(bp + 512); \
    bfr[2] = *(const short8*)(bp + 1024); bfr[3] = *(const short8*)(bp + 1536); }
#define RDA1(T, q) { \
    const short* ap = raB + ((T) & 3) * 4096 + (q) * 1024; \
    af[0] = *(const short8*)(ap); af[1] = *(const short8*)(ap + 512); }
#define MFMAQ1(q) { \
    __builtin_amdgcn_s_setprio(1); \
    _Pragma("unroll") for (int n = 0; n < 4; n++) { \
      acc[2*(q)][n]   = __builtin_amdgcn_mfma_f32_16x16x32_bf16(bfr[n], af[0], acc[2*(q)][n], 0, 0, 0); \
      acc[2*(q)+1][n] = __builtin_amdgcn_mfma_f32_16x16x32_bf16(bfr[n], af[1], acc[2*(q)+1][n], 0, 0, 0); } \
    __builtin_amdgcn_s_setprio(0); }
#define BARX1 { __builtin_amdgcn_s_barrier(); __builtin_amdgcn_sched_barrier(0); }
#define BAR21 { __builtin_amdgcn_s_barrier(); }

  // prologue: B(0)x2, A(0), A(1) -> 4 outstanding; VMW(1) drains T0, keeps A(1)
  STGB1(0); STGA1(0); STGA1(1);
  VMW(1);
  BAR21;

  for (int t = 0; t < NT - 2; ++t) {
    RDB1(t); RDA1(t, 0); STGB1(t + 1); BARX1; MFMAQ1(0); BAR21;
    RDA1(t, 1); STGA1(t + 2); VMW(1);  BARX1; MFMAQ1(1); BAR21;
  }
  { // peel tile NT-2: stage B(NT-1) only; VMW(0) publishes NT-1
    int t = NT - 2;
    RDB1(t); RDA1(t, 0); STGB1(t + 1); BARX1; MFMAQ1(0); BAR21;
    RDA1(t, 1); VMW(0);                BARX1; MFMAQ1(1); BAR21;
  }
  { // peel tile NT-1: no staging
    int t = NT - 1;
    RDB1(t); RDA1(t, 0); BARX1; MFMAQ1(0); BAR21;
    RDA1(t, 1);          BARX1; MFMAQ1(1);
  }
#undef STGA1
#undef STGB1
#undef RDB1
#undef RDA1
#undef MFMAQ1
#undef BARX1
#undef BAR21

  int row0 = bm * 128 + wr * 64, col0 = bn * 256 + wn * 64;
#pragma unroll
  for (int n = 0; n < 4; n++) {
    f32x4 bz = *(const f32x4*)(bias + col0 + n * 16 + g * 4);
#pragma unroll
    for (int m = 0; m < 4; m++)
#pragma unroll
      for (int r = 0; r < 4; r++) acc[m][n][r] += bz[r];
  }
  if (EPI == 0 && col0 < smLimit) {
#pragma unroll
    for (int m = 0; m < 4; m++) {
      float mx = acc[m][0][0];
#pragma unroll
      for (int n = 0; n < 4; n++)
#pragma unroll
        for (int r = 0; r < 4; r++) mx = fmaxf(mx, acc[m][n][r]);
      mx = fmaxf(mx, __shfl_xor(mx, 16));
      mx = fmaxf(mx, __shfl_xor(mx, 32));
      float s = 0.0f;
#pragma unroll
      for (int n = 0; n < 4; n++)
#pragma unroll
        for (int r = 0; r < 4; r++) {
          float e = __expf(acc[m][n][r] - mx);
          acc[m][n][r] = e; s += e;
        }
      s += __shfl_xor(s, 16);
      s += __shfl_xor(s, 32);
      float inv = 1.0f / s;
#pragma unroll
      for (int n = 0; n < 4; n++)
#pragma unroll
        for (int r = 0; r < 4; r++) acc[m][n][r] *= inv;
    }
  }
  if (EPI == 0 && ksumP != nullptr) {
    unsigned rel = (unsigned)(col0 - csBase);
    if (rel < 512u) {
      float* kp = ksumP + ((row0 / Trows) * 8 + (int)(rel >> 6)) * 64;
#pragma unroll
      for (int n = 0; n < 4; n++) {
        f32x4 s = acc[0][n];
#pragma unroll
        for (int m = 1; m < 4; m++)
#pragma unroll
          for (int r = 0; r < 4; r++) s[r] += acc[m][n][r];
#pragma unroll
        for (int msk = 1; msk < 16; msk <<= 1)
#pragma unroll
          for (int r = 0; r < 4; r++) s[r] += __shfl_xor(s[r], msk);
        if (l15 == 0)
#pragma unroll
          for (int r = 0; r < 4; r++)
            atomicAdd(kp + n * 16 + g * 4 + r, s[r]);
      }
    }
  }
  if (EPI == 1) {
#pragma unroll
    for (int m = 0; m < 4; m++)
#pragma unroll
      for (int n = 0; n < 4; n++)
#pragma unroll
        for (int r = 0; r < 4; r++) acc[m][n][r] = gelu_fast(acc[m][n][r]);
  }
#pragma unroll
  for (int m = 0; m < 4; m++) {
    int row = row0 + m * 16 + l15;
#pragma unroll
    for (int n = 0; n < 4; n++) {
      size_t base = (size_t)row * N + col0 + n * 16 + g * 4;
      if (EPI == 2) {
        f32x4 rv = *(const f32x4*)(resid + base);
        f32x4 o;
#pragma unroll
        for (int r = 0; r < 4; r++) o[r] = rv[r] + acc[m][n][r];
        *(f32x4*)((float*)outp + base) = o;
      } else {
        uint2 u;
        u.x = pk2(acc[m][n][0], acc[m][n][1]);
        u.y = pk2(acc[m][n][2], acc[m][n][3]);
        *(uint2*)((unsigned short*)outp + base) = u;
      }
    }
  }
}

// ---------------- ctx += k^T v per (b,h); grid = 32*parts, atomics into zeroed ctx
#define LDC 40
__launch_bounds__(256)
__global__ void ctx_kernel(const short* __restrict__ k, const short* __restrict__ v,
                           float* __restrict__ ctx, int T, int parts, int SD)
{
  __shared__ short kT[4][64 * LDC];
  __shared__ short vT[4][64 * LDC];
  int bh = blockIdx.x & 31, part = blockIdx.x >> 5;
  int b = bh >> 3, h = bh & 7;
  int tid = threadIdx.x, lane = tid & 63, wave = tid >> 6;
  int l15 = lane & 15, g = lane >> 4;
  int tlen = T / (4 * parts);
  int tbeg = (part * 4 + wave) * tlen;
  f32x4 acc[4][4] = {};
  short* myK = kT[wave];
  short* myV = vT[wave];
  for (int t0 = tbeg; t0 < tbeg + tlen; t0 += 32) {
#pragma unroll
    for (int j = 0; j < 4; j++) {
      int c = lane + j * 64;
      int r = c >> 3, d0 = (c & 7) * 8;
      short8 kv = *(const short8*)(k + (size_t)(b * T + t0 + r) * SD + h * 64 + d0);
      short8 vv = *(const short8*)(v + (size_t)(b * T + t0 + r) * SD + h * 64 + d0);
#pragma unroll
      for (int i = 0; i < 8; i++) {
        myK[(d0 + i) * LDC + r] = kv[i];
        myV[(d0 + i) * LDC + r] = vv[i];
      }
    }
    __syncthreads();
    short8 af[4], bfr[4];
#pragma unroll
    for (int m = 0; m < 4; m++) af[m]  = *(const short8*)(myK + (m * 16 + l15) * LDC + g * 8);
#pragma unroll
    for (int n = 0; n < 4; n++) bfr[n] = *(const short8*)(myV + (n * 16 + l15) * LDC + g * 8);
#pragma unroll
    for (int m = 0; m < 4; m++)
#pragma unroll
      for (int n = 0; n < 4; n++)
        acc[m][n] = __builtin_amdgcn_mfma_f32_16x16x32_bf16(af[m], bfr[n], acc[m][n], 0, 0, 0);
    __syncthreads();
  }
  float* cp = ctx + (size_t)bh * 64 * 64;
#pragma unroll
  for (int m = 0; m < 4; m++)
#pragma unroll
    for (int n = 0; n < 4; n++)
#pragma unroll
      for (int r = 0; r < 4; r++)
        atomicAdd(cp + (m * 16 + g * 4 + r) * 64 + (n * 16 + l15), acc[m][n][r]);
}

// ---------------- out[t,:] = q[t,:] + sum_br dinv(t) * (q[t,:] @ ctx[br])
#define LQ 72
__launch_bounds__(256)
__global__ void qctx_kernel(const short* __restrict__ q,
                            const float* __restrict__ ctx,   // [nb][32][64][64]
                            const float* __restrict__ ksum,  // [nb][32][64]
                            short* __restrict__ outp, int T, int nb, int SD)
{
  __shared__ short qs[128 * LQ];
  __shared__ short cT[2][64 * LQ];
  __shared__ float dls[2][128];
  int ntb = T >> 7;
  int bh = blockIdx.x / ntb, tq = blockIdx.x % ntb;
  int b = bh >> 3, h = bh & 7;
  int tid = threadIdx.x, lane = tid & 63, wave = tid >> 6;
  int l15 = lane & 15, g = lane >> 4;
  size_t qbase = (size_t)(b * T + tq * 128) * SD + h * 64;
  size_t obase = (size_t)(b * T + tq * 128) * CDIM + h * 64;

#pragma unroll
  for (int j = 0; j < 4; j++) {
    int c = tid + j * 256;
    int r = c >> 3, d0 = (c & 7) * 8;
    *(short8*)(qs + r * LQ + d0) = *(const short8*)(q + qbase + (size_t)r * SD + d0);
  }
  for (int br = 0; br < nb; br++) {
    const float* cp = ctx + ((size_t)br * 32 + bh) * 4096;
#pragma unroll
    for (int j = 0; j < 16; j++) {
      int e2 = tid + j * 256;
      int dd = e2 >> 6, ee = e2 & 63;
      cT[br][ee * LQ + dd] = f2b(cp[e2]);
    }
  }
  __syncthreads();

  int r0 = wave * 32;
  for (int br = 0; br < nb; br++) {
    int row = r0 + (lane >> 1);
    int dbase = (lane & 1) * 32;
    const float* kp = ksum + ((size_t)br * 32 + bh) * 64 + dbase;
    float s = 0.0f;
#pragma unroll
    for (int d = 0; d < 32; d++)
      s += b2f(qs[row * LQ + dbase + d]) * kp[d];
    s += __shfl_xor(s, 1);
    if (!(lane & 1)) dls[br][row] = 1.0f / fmaxf(s, 1e-9f);
  }

  short8 af[2][2];
#pragma unroll
  for (int m = 0; m < 2; m++)
#pragma unroll
    for (int kk = 0; kk < 2; kk++)
      af[m][kk] = *(const short8*)(qs + (r0 + m * 16 + l15) * LQ + kk * 32 + g * 8);

  float ofin[2][4][4];
#pragma unroll
  for (int m = 0; m < 2; m++)
#pragma unroll
    for (int n = 0; n < 4; n++)
#pragma unroll
      for (int r = 0; r < 4; r++)
        ofin[m][n][r] = b2f(qs[(r0 + m * 16 + g * 4 + r) * LQ + n * 16 + l15]);

  for (int br = 0; br < nb; br++) {
    f32x4 acc[2][4] = {};
#pragma unroll
    for (int kk = 0; kk < 2; kk++) {
      short8 bfr[4];
#pragma unroll
      for (int n = 0; n < 4; n++)
        bfr[n] = *(const short8*)(cT[br] + (n * 16 + l15) * LQ + kk * 32 + g * 8);
#pragma unroll
      for (int m = 0; m < 2; m++)
#pragma unroll
        for (int n = 0; n < 4; n++)
          acc[m][n] = __builtin_amdgcn_mfma_f32_16x16x32_bf16(af[m][kk], bfr[n], acc[m][n], 0, 0, 0);
    }
#pragma unroll
    for (int m = 0; m < 2; m++)
#pragma unroll
      for (int n = 0; n < 4; n++)
#pragma unroll
        for (int r = 0; r < 4; r++)
          ofin[m][n][r] += dls[br][r0 + m * 16 + g * 4 + r] * acc[m][n][r];
  }

#pragma unroll
  for (int m = 0; m < 2; m++)
#pragma unroll
    for (int n = 0; n < 4; n++)
#pragma unroll
      for (int r = 0; r < 4; r++) {
        int row = r0 + m * 16 + g * 4 + r;
        int col = n * 16 + l15;
        outp[obase + (size_t)row * CDIM + col] = f2b(ofin[m][n][r]);
      }
}

extern "C" void kernel_launch(void* const* d_in, const int* in_sizes, int n_in,
                              void* d_out, int out_size, void* d_ws, size_t ws_size,
                              hipStream_t stream)
{
  (void)in_sizes; (void)n_in; (void)out_size; (void)ws_size;
  const float* x     = (const float*)d_in[0];
  const float* y0    = (const float*)d_in[1];
  const float* y1    = (const float*)d_in[2];
  const float* ln1g  = (const float*)d_in[3];
  const float* ln1b  = (const float*)d_in[4];
  const float* ln20g = (const float*)d_in[5];
  const float* ln20b = (const float*)d_in[6];
  const float* ln21g = (const float*)d_in[7];
  const float* ln21b = (const float*)d_in[8];
  const float* ln3g  = (const float*)d_in[9];
  const float* ln3b  = (const float*)d_in[10];
  const float* ln4g  = (const float*)d_in[11];
  const float* ln4b  = (const float*)d_in[12];
  const float* ln5g  = (const float*)d_in[13];
  const float* ln5b  = (const float*)d_in[14];
  const float* caqw  = (const float*)d_in[15];
  const float* caqb  = (const float*)d_in[16];
  const float* cak0w = (const float*)d_in[17];
  const float* cak0b = (const float*)d_in[18];
  const float* cav0w = (const float*)d_in[19];
  const float* cav0b = (const float*)d_in[20];
  const float* cak1w = (const float*)d_in[21];
  const float* cak1b = (const float*)d_in[22];
  const float* cav1w = (const float*)d_in[23];
  const float* cav1b = (const float*)d_in[24];
  const float* capw  = (const float*)d_in[25];
  const float* capb  = (const float*)d_in[26];
  const float* saqw  = (const float*)d_in[27];
  const float* saqb  = (const float*)d_in[28];
  const float* sakw  = (const float*)d_in[29];
  const float* sakb  = (const float*)d_in[30];
  const float* savw  = (const float*)d_in[31];
  const float* savb  = (const float*)d_in[32];
  const float* sapw  = (const float*)d_in[33];
  const float* sapb  = (const float*)d_in[34];
  const float* m1w1  = (const float*)d_in[35];
  const float* m1b1  = (const float*)d_in[36];
  const float* m1w2  = (const float*)d_in[37];
  const float* m1b2  = (const float*)d_in[38];
  const float* m2w1  = (const float*)d_in[39];
  const float* m2b1  = (const float*)d_in[40];
  const float* m2w2  = (const float*)d_in[41];
  const float* m2b2  = (const float*)d_in[42];
  float* xout = (float*)d_out;

  char* p = (char*)d_ws;
  size_t off = 0;
  auto take = [&](size_t bytes) {
    char* r = p + off;
    off += (bytes + 255) & ~(size_t)255;
    return r;
  };
  const size_t W512 = (size_t)512 * 512 * 2;
  const size_t WMLP = (size_t)2048 * 512 * 2;
  short* wt_caq   = (short*)take(W512);
  short* wt_cakv0 = (short*)take(2 * W512);       // [k;v] 1024x512
  short* wt_cakv1 = (short*)take(2 * W512);
  short* wt_cap   = (short*)take(W512);
  short* wt_saqkv = (short*)take(3 * W512);       // [q;k;v] 1536x512
  short* wt_sap   = (short*)take(W512);
  short* wt_m1w1  = (short*)take(WMLP);
  short* wt_m1w2  = (short*)take(WMLP);
  short* wt_m2w1  = (short*)take(WMLP);
  short* wt_m2w2  = (short*)take(WMLP);
  float* b_saqkv  = (float*)take(1536 * 4);
  float* b_cakv0  = (float*)take(1024 * 4);
  float* b_cakv1  = (float*)take(1024 * 4);
  short* xn   = (short*)take((size_t)16384 * 512 * 2);
  short* bufD = (short*)take((size_t)16384 * 512 * 2);
  short* big  = (short*)take((size_t)16384 * 1536 * 2);   // CA: q@0, kv@+8M shorts; SA: qkv
  short* h1   = (short*)take((size_t)16384 * 2048 * 2);
  float* ksum = (float*)take((size_t)2 * 32 * 64 * 4);
  float* ctxb = (float*)take((size_t)2 * 32 * 64 * 64 * 4);

  short* q_ca  = big;
  short* kv_ca = big + (size_t)8 * 1024 * 1024;
  short* qkv   = big;

  const int MQ  = NBATCH * TQD;   // 16384
  const int MKV = NBATCH * TBD;   // 8192

  // ---- weight transpose+convert (single batched launch) ----
  {
    TcvtDesc d;
    const float* srcs[14] = {caqw, cak0w, cav0w, cak1w, cav1w, capw,
                             saqw, sakw, savw, sapw, m1w1, m1w2, m2w1, m2w2};
    short* dsts[14] = {wt_caq, wt_cakv0, wt_cakv0 + 512 * 512,
                       wt_cakv1, wt_cakv1 + 512 * 512, wt_cap,
                       wt_saqkv, wt_saqkv + 512 * 512, wt_saqkv + 2 * 512 * 512, wt_sap,
                       wt_m1w1, wt_m1w2, wt_m2w1, wt_m2w2};
    int Ks[14] = {512,512,512,512,512,512,512,512,512,512, 512,2048,512,2048};
    int Ns[14] = {512,512,512,512,512,512,512,512,512,512, 2048,512,2048,512};
    int total = 0;
    for (int i = 0; i < 14; i++) {
      d.src[i] = srcs[i]; d.dst[i] = dsts[i]; d.K[i] = Ks[i]; d.N[i] = Ns[i];
      d.nblk[i] = (Ks[i] >> 5) * (Ns[i] >> 5);
      total += d.nblk[i];
    }
    tcvt_all<<<total, 256, 0, stream>>>(d);
  }
  // ---- bias concats ----
  hipMemcpyAsync(b_saqkv,        saqb,  512 * 4, hipMemcpyDeviceToDevice, stream);
  hipMemcpyAsync(b_saqkv + 512,  sakb,  512 * 4, hipMemcpyDeviceToDevice, stream);
  hipMemcpyAsync(b_saqkv + 1024, savb,  512 * 4, hipMemcpyDeviceToDevice, stream);
  hipMemcpyAsync(b_cakv0,        cak0b, 512 * 4, hipMemcpyDeviceToDevice, stream);
  hipMemcpyAsync(b_cakv0 + 512,  cav0b, 512 * 4, hipMemcpyDeviceToDevice, stream);
  hipMemcpyAsync(b_cakv1,        cak1b, 512 * 4, hipMemcpyDeviceToDevice, stream);
  hipMemcpyAsync(b_cakv1 + 512,  cav1b, 512 * 4, hipMemcpyDeviceToDevice, stream);

  // ---- cross-attention ----
  ln_kernel<<<MQ / 4, 256, 0, stream>>>(x, ln1g, ln1b, xn);
  hipMemsetAsync(ksum, 0, (size_t)2 * 32 * 64 * 4, stream);
  hipMemsetAsync(ctxb, 0, (size_t)2 * 32 * 64 * 64 * 4, stream);
  gemm128<0><<<256, 512, 0, stream>>>(xn, wt_caq, caqb, nullptr, q_ca,
                                      MQ, 512, 512, 512, nullptr, 0, 0);
  for (int br = 0; br < 2; br++) {
    const float* yy = br ? y1 : y0;
    const float* lg = br ? ln21g : ln20g;
    const float* lb = br ? ln21b : ln20b;
    const short* wk = br ? wt_cakv1 : wt_cakv0;
    const float* bk = br ? b_cakv1 : b_cakv0;
    ln_kernel<<<MKV / 4, 256, 0, stream>>>(yy, lg, lb, bufD);
    gemm128<0><<<256, 512, 0, stream>>>(bufD, wk, bk, nullptr, kv_ca,
                                        MKV, 1024, 512, 512,
                                        ksum + (size_t)br * 2048, 0, TBD);
    ctx_kernel<<<256, 256, 0, stream>>>(kv_ca, kv_ca + 512,
                                        ctxb + (size_t)br * 32 * 4096, TBD, 8, 1024);
  }
  qctx_kernel<<<32 * (TQD / 128), 256, 0, stream>>>(q_ca, ctxb, ksum, bufD, TQD, 2, 512);
  gemm128<2><<<256, 512, 0, stream>>>(bufD, wt_cap, capb, x, xout,
                                      MQ, 512, 512, 0, nullptr, 0, 0);

  // ---- MLP 1 ----
  ln_kernel<<<MQ / 4, 256, 0, stream>>>(xout, ln3g, ln3b, xn);
  gemm128<1><<<1024, 512, 0, stream>>>(xn, wt_m1w1, m1b1, nullptr, h1,
                                       MQ, 2048, 512, 0, nullptr, 0, 0);
  gemm128<2><<<256, 512, 0, stream>>>(h1, wt_m1w2, m1b2, xout, xout,
                                      MQ, 512, 2048, 0, nullptr, 0, 0);

  // ---- self-attention (fused q|k|v projection; k-colsum fused) ----
  ln_kernel<<<MQ / 4, 256, 0, stream>>>(xout, ln4g, ln4b, xn);
  hipMemsetAsync(ksum, 0, (size_t)32 * 64 * 4, stream);
  hipMemsetAsync(ctxb, 0, (size_t)32 * 64 * 64 * 4, stream);
  gemm128<0><<<768, 512, 0, stream>>>(xn, wt_saqkv, b_saqkv, nullptr, qkv,
                                      MQ, 1536, 512, 1024, ksum, 512, TQD);
  ctx_kernel<<<256, 256, 0, stream>>>(qkv + 512, qkv + 1024, ctxb, TQD, 8, 1536);
  qctx_kernel<<<32 * (TQD / 128), 256, 0, stream>>>(qkv, ctxb, ksum, bufD, TQD, 1, 1536);
  gemm128<2><<<256, 512, 0, stream>>>(bufD, wt_sap, sapb, xout, xout,
                                      MQ, 512, 512, 0, nullptr, 0, 0);

  // ---- MLP 2 ----
  ln_kernel<<<MQ / 4, 256, 0, stream>>>(xout, ln5g, ln5b, xn);
  gemm128<1><<<1024, 512, 0, stream>>>(xn, wt_m2w1, m2b1, nullptr, h1,
                                       MQ, 2048, 512, 0, nullptr, 0, 0);
  gemm128<2><<<256, 512, 0, stream>>>(h1, wt_m2w2, m2b2, xout, xout,
                                      MQ, 512, 2048, 0, nullptr, 0, 0);
}

// Round 9
// 559.129 us; speedup vs baseline: 1.2831x; 1.0082x over previous
//
#include <hip/hip_runtime.h>
#include <hip/hip_bf16.h>
#include <math.h>

// Problem constants
#define NBATCH 4
#define TQD 4096
#define TBD 2048
#define CDIM 512
#define NH 8
#define HD 64
#define NINNER 2048

using short8 = __attribute__((ext_vector_type(8))) short;
using f32x4  = __attribute__((ext_vector_type(4))) float;

__device__ __forceinline__ float b2f(short s) {
  return __uint_as_float(((unsigned)(unsigned short)s) << 16);
}
__device__ __forceinline__ short f2b(float f) {
  unsigned u = __float_as_uint(f);
  return (short)((u + 0x7FFFu + ((u >> 16) & 1u)) >> 16);
}
__device__ __forceinline__ unsigned pk2(float a, float b) {
  float2 t; t.x = a; t.y = b;
  __hip_bfloat162 h = __float22bfloat162_rn(t);
  return *(unsigned*)&h;
}
__device__ __forceinline__ float gelu_fast(float x) {
  float x3 = x * x * x;
  float y2 = 1.5957691216f * (x + 0.044715f * x3);
  float e = __expf(y2);
  return x * e / (e + 1.0f);
}
__device__ __forceinline__ void gload16(const short* g, short* l) {
  __builtin_amdgcn_global_load_lds((const __attribute__((address_space(1))) void*)g,
                                   (__attribute__((address_space(3))) void*)l, 16, 0, 0);
}

// ---------------- LayerNorm (fp32 in -> bf16 out), wave-per-row, 4 rows/block
__launch_bounds__(256)
__global__ void ln_kernel(const float* __restrict__ x, const float* __restrict__ g,
                          const float* __restrict__ b, short* __restrict__ out)
{
  int row = blockIdx.x * 4 + (threadIdx.x >> 6);
  int lane = threadIdx.x & 63;
  const float4* xp = (const float4*)(x + (size_t)row * CDIM);
  float4 v0 = xp[lane], v1 = xp[lane + 64];
  float s  = v0.x + v0.y + v0.z + v0.w + v1.x + v1.y + v1.z + v1.w;
  float s2 = v0.x * v0.x + v0.y * v0.y + v0.z * v0.z + v0.w * v0.w
           + v1.x * v1.x + v1.y * v1.y + v1.z * v1.z + v1.w * v1.w;
#pragma unroll
  for (int m = 1; m < 64; m <<= 1) { s += __shfl_xor(s, m); s2 += __shfl_xor(s2, m); }
  float mean = s * (1.0f / CDIM);
  float var  = s2 * (1.0f / CDIM) - mean * mean;
  float inv  = rsqrtf(var + 1e-5f);
  float4 g0 = ((const float4*)g)[lane], g1 = ((const float4*)g)[lane + 64];
  float4 b0 = ((const float4*)b)[lane], b1 = ((const float4*)b)[lane + 64];
  uint2 o0, o1;
  o0.x = pk2((v0.x - mean) * inv * g0.x + b0.x, (v0.y - mean) * inv * g0.y + b0.y);
  o0.y = pk2((v0.z - mean) * inv * g0.z + b0.z, (v0.w - mean) * inv * g0.w + b0.w);
  o1.x = pk2((v1.x - mean) * inv * g1.x + b1.x, (v1.y - mean) * inv * g1.y + b1.y);
  o1.y = pk2((v1.z - mean) * inv * g1.z + b1.z, (v1.w - mean) * inv * g1.w + b1.w);
  uint2* op = (uint2*)(out + (size_t)row * CDIM);
  op[lane] = o0;
  op[lane + 64] = o1;
}

// ---------------- batched transpose+convert: W[K][N] f32 -> Wt[N][K] bf16
struct TcvtDesc {
  const float* src[14];
  short* dst[14];
  int K[14], N[14], nblk[14];
};
__launch_bounds__(256)
__global__ void tcvt_all(TcvtDesc d)
{
  int blk = blockIdx.x, wi = 0;
  while (blk >= d.nblk[wi]) { blk -= d.nblk[wi]; wi++; }
  const float* __restrict__ W = d.src[wi];
  short* __restrict__ Wt = d.dst[wi];
  int K = d.K[wi], N = d.N[wi];
  __shared__ float t[32][33];
  int nbk = K >> 5;
  int bk = blk % nbk, bn = blk / nbk;
  int cx = threadIdx.x & 31, cy = threadIdx.x >> 5;
#pragma unroll
  for (int i = 0; i < 4; i++)
    t[cy + 8 * i][cx] = W[(size_t)(bk * 32 + cy + 8 * i) * N + bn * 32 + cx];
  __syncthreads();
#pragma unroll
  for (int i = 0; i < 4; i++)
    Wt[(size_t)(bn * 32 + cy + 8 * i) * K + bk * 32 + cx] = f2b(t[cx][cy + 8 * i]);
}

#define VMW(n) asm volatile("s_waitcnt vmcnt(" #n ")" ::: "memory");

// ======== 128 x (NF*64) GEMM, BK=32, 2 phases/K-tile, 2 blocks/CU ===========
// NF=4: BN=256 (LDS 80KB); NF=2: BN=128 (LDS 56KB). A quad-buffered
// [4][128][32]; B TRIPLE-buffered [3][BN][32] -> stage AB(t+2) at t:ph0,
// drain with counted VMW(L) at t:ph1 (L = 1 + NF/2 loads/tile) => cover = 3
// phase-boundaries (~latency of L3/HBM activation loads). Ledger (steady):
// enter ph0 = L {AB(t+1)}; ph0 +L = 2L; ph1 VMW(L) drains oldest L = AB(t+1)
// (publish at ph1's barrier, read t+1:ph0); keeps AB(t+2).
// WAR: B buf (t+2)%3 last read t-1:ph0 (2 barriers prior); A buf (t+2)&3
// last read t-2:ph1. Peel last 2 tiles (VMW(0) at NT-2:ph1).
// Swizzle slot^=((row>>1)&3) both sides (r4-proven).
// EPI: 0 = bf16 + softmax per 64-col head chunk where col<smLimit (NF=2:
// cross-wave-pair exchange via LDS) + fused k-colsum when ksumP!=null
// (cols [csBase,csBase+512)); 1 = gelu bf16; 2 = residual-add fp32.
template<int EPI, int NF>
__launch_bounds__(512, 4)
__global__ void gemm128(const short* __restrict__ A, const short* __restrict__ Bt,
                        const float* __restrict__ bias, const float* __restrict__ resid,
                        void* __restrict__ outp, int M, int N, int K, int smLimit,
                        float* __restrict__ ksumP, int csBase, int Trows)
{
  constexpr int BUFB = NF * 2048;           // shorts per B buffer
  __shared__ short As[4 * 4096];            // 4 bufs x [128][32]
  __shared__ short Bs[3 * BUFB];            // 3 bufs x [NF*64][32]
  int tid = threadIdx.x, lane = tid & 63, wave = tid >> 6;
  int l15 = lane & 15, g = lane >> 4;
  int wr = wave >> 2, wn = wave & 3;
  int nbn = N / (NF * 64);
  int per = gridDim.x >> 3;
  int wg = (blockIdx.x & 7) * per + (blockIdx.x >> 3);
  int bm = wg / nbn, bn = wg % nbn;
  f32x4 acc[4][NF] = {};

  int srcslot = ((lane & 3) ^ ((lane >> 3) & 3)) * 8;
  const short* gA0 = A  + (size_t)(bm * 128 + wave * 16 + (lane >> 2)) * K + srcslot;
  const short* gB0 = Bt + (size_t)(bn * (NF * 64) + wave * 16 + (lane >> 2)) * K + srcslot;
  const short* gB1 = gB0 + (size_t)128 * K;   // NF=4 only
  short* lA = As + wave * 512;
  short* lB = Bs + wave * 512;

  int rsw = (g ^ ((l15 >> 1) & 3)) * 8;
  const short* raB = As + (wr * 64 + l15) * 32 + rsw;
  const short* rbB = Bs + (wn * (NF * 16) + l15) * 32 + rsw;

  short8 af[2], bfr[NF];
  int NT = K >> 5;

#define STGA1(T) gload16(gA0 + (size_t)(T) * 32, lA + ((T) & 3) * 4096);
#define STGB1(T) { \
    gload16(gB0 + (size_t)(T) * 32, lB + ((T) % 3) * BUFB); \
    if constexpr (NF == 4) gload16(gB1 + (size_t)(T) * 32, lB + ((T) % 3) * BUFB + 4096); }
#define RDB1(T) { \
    const short* bp = rbB + ((T) % 3) * BUFB; \
    _Pragma("unroll") for (int n = 0; n < NF; n++) \
      bfr[n] = *(const short8*)(bp + n * 512); }
#define RDA1(T, q) { \
    const short* ap = raB + ((T) & 3) * 4096 + (q) * 1024; \
    af[0] = *(const short8*)(ap); af[1] = *(const short8*)(ap + 512); }
#define MFMAQ1(q) { \
    __builtin_amdgcn_s_setprio(1); \
    _Pragma("unroll") for (int n = 0; n < NF; n++) { \
      acc[2*(q)][n]   = __builtin_amdgcn_mfma_f32_16x16x32_bf16(bfr[n], af[0], acc[2*(q)][n], 0, 0, 0); \
      acc[2*(q)+1][n] = __builtin_amdgcn_mfma_f32_16x16x32_bf16(bfr[n], af[1], acc[2*(q)+1][n], 0, 0, 0); } \
    __builtin_amdgcn_s_setprio(0); }
#define VMW_S { if constexpr (NF == 4) { VMW(3) } else { VMW(2) } }
#define BARX1 { __builtin_amdgcn_s_barrier(); __builtin_amdgcn_sched_barrier(0); }
#define BAR21 { __builtin_amdgcn_s_barrier(); }

  // prologue: AB(0), AB(1) -> 2L outstanding; VMW(L) drains AB(0)
  STGA1(0); STGB1(0);
  STGA1(1); STGB1(1);
  VMW_S;
  BAR21;

  for (int t = 0; t < NT - 2; ++t) {
    RDB1(t); RDA1(t, 0); STGA1(t + 2); STGB1(t + 2); BARX1; MFMAQ1(0); BAR21;
    RDA1(t, 1); VMW_S;                               BARX1; MFMAQ1(1); BAR21;
  }
  { // peel tile NT-2: no staging; VMW(0) publishes NT-1
    int t = NT - 2;
    RDB1(t); RDA1(t, 0); BARX1; MFMAQ1(0); BAR21;
    RDA1(t, 1); VMW(0);  BARX1; MFMAQ1(1); BAR21;
  }
  { // peel tile NT-1
    int t = NT - 1;
    RDB1(t); RDA1(t, 0); BARX1; MFMAQ1(0); BAR21;
    RDA1(t, 1);          BARX1; MFMAQ1(1);
  }
#undef STGA1
#undef STGB1
#undef RDB1
#undef RDA1
#undef MFMAQ1
#undef VMW_S
#undef BARX1
#undef BAR21

  int row0 = bm * 128 + wr * 64, col0 = bn * (NF * 64) + wn * (NF * 16);
#pragma unroll
  for (int n = 0; n < NF; n++) {
    f32x4 bz = *(const f32x4*)(bias + col0 + n * 16 + g * 4);
#pragma unroll
    for (int m = 0; m < 4; m++)
#pragma unroll
      for (int r = 0; r < 4; r++) acc[m][n][r] += bz[r];
  }
  if (EPI == 0) {
    bool insm = (bn * (NF * 64) < smLimit);    // block-uniform
    if constexpr (NF == 4) {
      if (insm) {
#pragma unroll
        for (int m = 0; m < 4; m++) {
          float mx = acc[m][0][0];
#pragma unroll
          for (int n = 0; n < 4; n++)
#pragma unroll
            for (int r = 0; r < 4; r++) mx = fmaxf(mx, acc[m][n][r]);
          mx = fmaxf(mx, __shfl_xor(mx, 16));
          mx = fmaxf(mx, __shfl_xor(mx, 32));
          float s = 0.0f;
#pragma unroll
          for (int n = 0; n < 4; n++)
#pragma unroll
            for (int r = 0; r < 4; r++) {
              float e = __expf(acc[m][n][r] - mx);
              acc[m][n][r] = e; s += e;
            }
          s += __shfl_xor(s, 16);
          s += __shfl_xor(s, 32);
          float inv = 1.0f / s;
#pragma unroll
          for (int n = 0; n < 4; n++)
#pragma unroll
            for (int r = 0; r < 4; r++) acc[m][n][r] *= inv;
        }
      }
    } else {
      // NF=2: 64-col head chunk spans wave pair (wave, wave^1). Exchange
      // partial max/sum via LDS (As reused; safe: all waves past their own
      // lgkm drains; __syncthreads provides the fences).
      if (insm) {
        float* xch = (float*)As;               // [8 waves][4 m][16 l15]
        float pm[4], ps[4];
#pragma unroll
        for (int m = 0; m < 4; m++) {
          float mx = acc[m][0][0];
#pragma unroll
          for (int n = 0; n < 2; n++)
#pragma unroll
            for (int r = 0; r < 4; r++) mx = fmaxf(mx, acc[m][n][r]);
          mx = fmaxf(mx, __shfl_xor(mx, 16));
          mx = fmaxf(mx, __shfl_xor(mx, 32));
          pm[m] = mx;
        }
        __syncthreads();
        if (g == 0)
#pragma unroll
          for (int m = 0; m < 4; m++) xch[wave * 64 + m * 16 + l15] = pm[m];
        __syncthreads();
#pragma unroll
        for (int m = 0; m < 4; m++)
          pm[m] = fmaxf(pm[m], xch[(wave ^ 1) * 64 + m * 16 + l15]);
#pragma unroll
        for (int m = 0; m < 4; m++) {
          float s = 0.0f;
#pragma unroll
          for (int n = 0; n < 2; n++)
#pragma unroll
            for (int r = 0; r < 4; r++) {
              float e = __expf(acc[m][n][r] - pm[m]);
              acc[m][n][r] = e; s += e;
            }
          s += __shfl_xor(s, 16);
          s += __shfl_xor(s, 32);
          ps[m] = s;
        }
        __syncthreads();
        if (g == 0)
#pragma unroll
          for (int m = 0; m < 4; m++) xch[wave * 64 + m * 16 + l15] = ps[m];
        __syncthreads();
#pragma unroll
        for (int m = 0; m < 4; m++) {
          float inv = 1.0f / (ps[m] + xch[(wave ^ 1) * 64 + m * 16 + l15]);
#pragma unroll
          for (int n = 0; n < 2; n++)
#pragma unroll
            for (int r = 0; r < 4; r++) acc[m][n][r] *= inv;
        }
      }
    }
  }
  if (EPI == 0 && ksumP != nullptr) {
    unsigned rel = (unsigned)(col0 - csBase);
    if (rel < 512u) {
      float* kp = ksumP + ((row0 / Trows) * 8 + (int)(rel >> 6)) * 64 + (int)(rel & 63u);
#pragma unroll
      for (int n = 0; n < NF; n++) {
        f32x4 s = acc[0][n];
#pragma unroll
        for (int m = 1; m < 4; m++)
#pragma unroll
          for (int r = 0; r < 4; r++) s[r] += acc[m][n][r];
#pragma unroll
        for (int msk = 1; msk < 16; msk <<= 1)
#pragma unroll
          for (int r = 0; r < 4; r++) s[r] += __shfl_xor(s[r], msk);
        if (l15 == 0)
#pragma unroll
          for (int r = 0; r < 4; r++)
            atomicAdd(kp + n * 16 + g * 4 + r, s[r]);
      }
    }
  }
  if (EPI == 1) {
#pragma unroll
    for (int m = 0; m < 4; m++)
#pragma unroll
      for (int n = 0; n < NF; n++)
#pragma unroll
        for (int r = 0; r < 4; r++) acc[m][n][r] = gelu_fast(acc[m][n][r]);
  }
#pragma unroll
  for (int m = 0; m < 4; m++) {
    int row = row0 + m * 16 + l15;
#pragma unroll
    for (int n = 0; n < NF; n++) {
      size_t base = (size_t)row * N + col0 + n * 16 + g * 4;
      if (EPI == 2) {
        f32x4 rv = *(const f32x4*)(resid + base);
        f32x4 o;
#pragma unroll
        for (int r = 0; r < 4; r++) o[r] = rv[r] + acc[m][n][r];
        *(f32x4*)((float*)outp + base) = o;
      } else {
        uint2 u;
        u.x = pk2(acc[m][n][0], acc[m][n][1]);
        u.y = pk2(acc[m][n][2], acc[m][n][3]);
        *(uint2*)((unsigned short*)outp + base) = u;
      }
    }
  }
}

// ---------------- ctx += k^T v per (b,h); grid = 32*parts, atomics into zeroed ctx
#define LDC 40
__launch_bounds__(256)
__global__ void ctx_kernel(const short* __restrict__ k, const short* __restrict__ v,
                           float* __restrict__ ctx, int T, int parts, int SD)
{
  __shared__ short kT[4][64 * LDC];
  __shared__ short vT[4][64 * LDC];
  int bh = blockIdx.x & 31, part = blockIdx.x >> 5;
  int b = bh >> 3, h = bh & 7;
  int tid = threadIdx.x, lane = tid & 63, wave = tid >> 6;
  int l15 = lane & 15, g = lane >> 4;
  int tlen = T / (4 * parts);
  int tbeg = (part * 4 + wave) * tlen;
  f32x4 acc[4][4] = {};
  short* myK = kT[wave];
  short* myV = vT[wave];
  for (int t0 = tbeg; t0 < tbeg + tlen; t0 += 32) {
#pragma unroll
    for (int j = 0; j < 4; j++) {
      int c = lane + j * 64;
      int r = c >> 3, d0 = (c & 7) * 8;
      short8 kv = *(const short8*)(k + (size_t)(b * T + t0 + r) * SD + h * 64 + d0);
      short8 vv = *(const short8*)(v + (size_t)(b * T + t0 + r) * SD + h * 64 + d0);
#pragma unroll
      for (int i = 0; i < 8; i++) {
        myK[(d0 + i) * LDC + r] = kv[i];
        myV[(d0 + i) * LDC + r] = vv[i];
      }
    }
    __syncthreads();
    short8 af[4], bfr[4];
#pragma unroll
    for (int m = 0; m < 4; m++) af[m]  = *(const short8*)(myK + (m * 16 + l15) * LDC + g * 8);
#pragma unroll
    for (int n = 0; n < 4; n++) bfr[n] = *(const short8*)(myV + (n * 16 + l15) * LDC + g * 8);
#pragma unroll
    for (int m = 0; m < 4; m++)
#pragma unroll
      for (int n = 0; n < 4; n++)
        acc[m][n] = __builtin_amdgcn_mfma_f32_16x16x32_bf16(af[m], bfr[n], acc[m][n], 0, 0, 0);
    __syncthreads();
  }
  float* cp = ctx + (size_t)bh * 64 * 64;
#pragma unroll
  for (int m = 0; m < 4; m++)
#pragma unroll
    for (int n = 0; n < 4; n++)
#pragma unroll
      for (int r = 0; r < 4; r++)
        atomicAdd(cp + (m * 16 + g * 4 + r) * 64 + (n * 16 + l15), acc[m][n][r]);
}

// ---------------- out[t,:] = q[t,:] + sum_br dinv(t) * (q[t,:] @ ctx[br])
#define LQ 72
__launch_bounds__(256)
__global__ void qctx_kernel(const short* __restrict__ q,
                            const float* __restrict__ ctx,   // [nb][32][64][64]
                            const float* __restrict__ ksum,  // [nb][32][64]
                            short* __restrict__ outp, int T, int nb, int SD)
{
  __shared__ short qs[128 * LQ];
  __shared__ short cT[2][64 * LQ];
  __shared__ float dls[2][128];
  int ntb = T >> 7;
  int bh = blockIdx.x / ntb, tq = blockIdx.x % ntb;
  int b = bh >> 3, h = bh & 7;
  int tid = threadIdx.x, lane = tid & 63, wave = tid >> 6;
  int l15 = lane & 15, g = lane >> 4;
  size_t qbase = (size_t)(b * T + tq * 128) * SD + h * 64;
  size_t obase = (size_t)(b * T + tq * 128) * CDIM + h * 64;

#pragma unroll
  for (int j = 0; j < 4; j++) {
    int c = tid + j * 256;
    int r = c >> 3, d0 = (c & 7) * 8;
    *(short8*)(qs + r * LQ + d0) = *(const short8*)(q + qbase + (size_t)r * SD + d0);
  }
  for (int br = 0; br < nb; br++) {
    const float* cp = ctx + ((size_t)br * 32 + bh) * 4096;
#pragma unroll
    for (int j = 0; j < 16; j++) {
      int e2 = tid + j * 256;
      int dd = e2 >> 6, ee = e2 & 63;
      cT[br][ee * LQ + dd] = f2b(cp[e2]);
    }
  }
  __syncthreads();

  int r0 = wave * 32;
  for (int br = 0; br < nb; br++) {
    int row = r0 + (lane >> 1);
    int dbase = (lane & 1) * 32;
    const float* kp = ksum + ((size_t)br * 32 + bh) * 64 + dbase;
    float s = 0.0f;
#pragma unroll
    for (int d = 0; d < 32; d++)
      s += b2f(qs[row * LQ + dbase + d]) * kp[d];
    s += __shfl_xor(s, 1);
    if (!(lane & 1)) dls[br][row] = 1.0f / fmaxf(s, 1e-9f);
  }

  short8 af[2][2];
#pragma unroll
  for (int m = 0; m < 2; m++)
#pragma unroll
    for (int kk = 0; kk < 2; kk++)
      af[m][kk] = *(const short8*)(qs + (r0 + m * 16 + l15) * LQ + kk * 32 + g * 8);

  float ofin[2][4][4];
#pragma unroll
  for (int m = 0; m < 2; m++)
#pragma unroll
    for (int n = 0; n < 4; n++)
#pragma unroll
      for (int r = 0; r < 4; r++)
        ofin[m][n][r] = b2f(qs[(r0 + m * 16 + g * 4 + r) * LQ + n * 16 + l15]);

  for (int br = 0; br < nb; br++) {
    f32x4 acc[2][4] = {};
#pragma unroll
    for (int kk = 0; kk < 2; kk++) {
      short8 bfr[4];
#pragma unroll
      for (int n = 0; n < 4; n++)
        bfr[n] = *(const short8*)(cT[br] + (n * 16 + l15) * LQ + kk * 32 + g * 8);
#pragma unroll
      for (int m = 0; m < 2; m++)
#pragma unroll
        for (int n = 0; n < 4; n++)
          acc[m][n] = __builtin_amdgcn_mfma_f32_16x16x32_bf16(af[m][kk], bfr[n], acc[m][n], 0, 0, 0);
    }
#pragma unroll
    for (int m = 0; m < 2; m++)
#pragma unroll
      for (int n = 0; n < 4; n++)
#pragma unroll
        for (int r = 0; r < 4; r++)
          ofin[m][n][r] += dls[br][r0 + m * 16 + g * 4 + r] * acc[m][n][r];
  }

#pragma unroll
  for (int m = 0; m < 2; m++)
#pragma unroll
    for (int n = 0; n < 4; n++)
#pragma unroll
      for (int r = 0; r < 4; r++) {
        int row = r0 + m * 16 + g * 4 + r;
        int col = n * 16 + l15;
        outp[obase + (size_t)row * CDIM + col] = f2b(ofin[m][n][r]);
      }
}

extern "C" void kernel_launch(void* const* d_in, const int* in_sizes, int n_in,
                              void* d_out, int out_size, void* d_ws, size_t ws_size,
                              hipStream_t stream)
{
  (void)in_sizes; (void)n_in; (void)out_size; (void)ws_size;
  const float* x     = (const float*)d_in[0];
  const float* y0    = (const float*)d_in[1];
  const float* y1    = (const float*)d_in[2];
  const float* ln1g  = (const float*)d_in[3];
  const float* ln1b  = (const float*)d_in[4];
  const float* ln20g = (const float*)d_in[5];
  const float* ln20b = (const float*)d_in[6];
  const float* ln21g = (const float*)d_in[7];
  const float* ln21b = (const float*)d_in[8];
  const float* ln3g  = (const float*)d_in[9];
  const float* ln3b  = (const float*)d_in[10];
  const float* ln4g  = (const float*)d_in[11];
  const float* ln4b  = (const float*)d_in[12];
  const float* ln5g  = (const float*)d_in[13];
  const float* ln5b  = (const float*)d_in[14];
  const float* caqw  = (const float*)d_in[15];
  const float* caqb  = (const float*)d_in[16];
  const float* cak0w = (const float*)d_in[17];
  const float* cak0b = (const float*)d_in[18];
  const float* cav0w = (const float*)d_in[19];
  const float* cav0b = (const float*)d_in[20];
  const float* cak1w = (const float*)d_in[21];
  const float* cak1b = (const float*)d_in[22];
  const float* cav1w = (const float*)d_in[23];
  const float* cav1b = (const float*)d_in[24];
  const float* capw  = (const float*)d_in[25];
  const float* capb  = (const float*)d_in[26];
  const float* saqw  = (const float*)d_in[27];
  const float* saqb  = (const float*)d_in[28];
  const float* sakw  = (const float*)d_in[29];
  const float* sakb  = (const float*)d_in[30];
  const float* savw  = (const float*)d_in[31];
  const float* savb  = (const float*)d_in[32];
  const float* sapw  = (const float*)d_in[33];
  const float* sapb  = (const float*)d_in[34];
  const float* m1w1  = (const float*)d_in[35];
  const float* m1b1  = (const float*)d_in[36];
  const float* m1w2  = (const float*)d_in[37];
  const float* m1b2  = (const float*)d_in[38];
  const float* m2w1  = (const float*)d_in[39];
  const float* m2b1  = (const float*)d_in[40];
  const float* m2w2  = (const float*)d_in[41];
  const float* m2b2  = (const float*)d_in[42];
  float* xout = (float*)d_out;

  char* p = (char*)d_ws;
  size_t off = 0;
  auto take = [&](size_t bytes) {
    char* r = p + off;
    off += (bytes + 255) & ~(size_t)255;
    return r;
  };
  const size_t W512 = (size_t)512 * 512 * 2;
  const size_t WMLP = (size_t)2048 * 512 * 2;
  short* wt_caq   = (short*)take(W512);
  short* wt_cakv0 = (short*)take(2 * W512);       // [k;v] 1024x512
  short* wt_cakv1 = (short*)take(2 * W512);
  short* wt_cap   = (short*)take(W512);
  short* wt_saqkv = (short*)take(3 * W512);       // [q;k;v] 1536x512
  short* wt_sap   = (short*)take(W512);
  short* wt_m1w1  = (short*)take(WMLP);
  short* wt_m1w2  = (short*)take(WMLP);
  short* wt_m2w1  = (short*)take(WMLP);
  short* wt_m2w2  = (short*)take(WMLP);
  float* b_saqkv  = (float*)take(1536 * 4);
  float* b_cakv0  = (float*)take(1024 * 4);
  float* b_cakv1  = (float*)take(1024 * 4);
  short* xn   = (short*)take((size_t)16384 * 512 * 2);
  short* bufD = (short*)take((size_t)16384 * 512 * 2);
  short* big  = (short*)take((size_t)16384 * 1536 * 2);   // CA: q@0, kv@+8M shorts; SA: qkv
  short* h1   = (short*)take((size_t)16384 * 2048 * 2);
  float* ksum = (float*)take((size_t)2 * 32 * 64 * 4);
  float* ctxb = (float*)take((size_t)2 * 32 * 64 * 64 * 4);

  short* q_ca  = big;
  short* kv_ca = big + (size_t)8 * 1024 * 1024;
  short* qkv   = big;

  const int MQ  = NBATCH * TQD;   // 16384
  const int MKV = NBATCH * TBD;   // 8192

  // ---- weight transpose+convert (single batched launch) ----
  {
    TcvtDesc d;
    const float* srcs[14] = {caqw, cak0w, cav0w, cak1w, cav1w, capw,
                             saqw, sakw, savw, sapw, m1w1, m1w2, m2w1, m2w2};
    short* dsts[14] = {wt_caq, wt_cakv0, wt_cakv0 + 512 * 512,
                       wt_cakv1, wt_cakv1 + 512 * 512, wt_cap,
                       wt_saqkv, wt_saqkv + 512 * 512, wt_saqkv + 2 * 512 * 512, wt_sap,
                       wt_m1w1, wt_m1w2, wt_m2w1, wt_m2w2};
    int Ks[14] = {512,512,512,512,512,512,512,512,512,512, 512,2048,512,2048};
    int Ns[14] = {512,512,512,512,512,512,512,512,512,512, 2048,512,2048,512};
    int total = 0;
    for (int i = 0; i < 14; i++) {
      d.src[i] = srcs[i]; d.dst[i] = dsts[i]; d.K[i] = Ks[i]; d.N[i] = Ns[i];
      d.nblk[i] = (Ks[i] >> 5) * (Ns[i] >> 5);
      total += d.nblk[i];
    }
    tcvt_all<<<total, 256, 0, stream>>>(d);
  }
  // ---- bias concats ----
  hipMemcpyAsync(b_saqkv,        saqb,  512 * 4, hipMemcpyDeviceToDevice, stream);
  hipMemcpyAsync(b_saqkv + 512,  sakb,  512 * 4, hipMemcpyDeviceToDevice, stream);
  hipMemcpyAsync(b_saqkv + 1024, savb,  512 * 4, hipMemcpyDeviceToDevice, stream);
  hipMemcpyAsync(b_cakv0,        cak0b, 512 * 4, hipMemcpyDeviceToDevice, stream);
  hipMemcpyAsync(b_cakv0 + 512,  cav0b, 512 * 4, hipMemcpyDeviceToDevice, stream);
  hipMemcpyAsync(b_cakv1,        cak1b, 512 * 4, hipMemcpyDeviceToDevice, stream);
  hipMemcpyAsync(b_cakv1 + 512,  cav1b, 512 * 4, hipMemcpyDeviceToDevice, stream);

  // ---- cross-attention ----
  ln_kernel<<<MQ / 4, 256, 0, stream>>>(x, ln1g, ln1b, xn);
  hipMemsetAsync(ksum, 0, (size_t)2 * 32 * 64 * 4, stream);
  hipMemsetAsync(ctxb, 0, (size_t)2 * 32 * 64 * 64 * 4, stream);
  gemm128<0, 2><<<512, 512, 0, stream>>>(xn, wt_caq, caqb, nullptr, q_ca,
                                         MQ, 512, 512, 512, nullptr, 0, 0);
  for (int br = 0; br < 2; br++) {
    const float* yy = br ? y1 : y0;
    const float* lg = br ? ln21g : ln20g;
    const float* lb = br ? ln21b : ln20b;
    const short* wk = br ? wt_cakv1 : wt_cakv0;
    const float* bk = br ? b_cakv1 : b_cakv0;
    ln_kernel<<<MKV / 4, 256, 0, stream>>>(yy, lg, lb, bufD);
    gemm128<0, 2><<<512, 512, 0, stream>>>(bufD, wk, bk, nullptr, kv_ca,
                                           MKV, 1024, 512, 512,
                                           ksum + (size_t)br * 2048, 0, TBD);
    ctx_kernel<<<256, 256, 0, stream>>>(kv_ca, kv_ca + 512,
                                        ctxb + (size_t)br * 32 * 4096, TBD, 8, 1024);
  }
  qctx_kernel<<<32 * (TQD / 128), 256, 0, stream>>>(q_ca, ctxb, ksum, bufD, TQD, 2, 512);
  gemm128<2, 2><<<512, 512, 0, stream>>>(bufD, wt_cap, capb, x, xout,
                                         MQ, 512, 512, 0, nullptr, 0, 0);

  // ---- MLP 1 ----
  ln_kernel<<<MQ / 4, 256, 0, stream>>>(xout, ln3g, ln3b, xn);
  gemm128<1, 4><<<1024, 512, 0, stream>>>(xn, wt_m1w1, m1b1, nullptr, h1,
                                          MQ, 2048, 512, 0, nullptr, 0, 0);
  gemm128<2, 2><<<512, 512, 0, stream>>>(h1, wt_m1w2, m1b2, xout, xout,
                                         MQ, 512, 2048, 0, nullptr, 0, 0);

  // ---- self-attention (fused q|k|v projection; k-colsum fused) ----
  ln_kernel<<<MQ / 4, 256, 0, stream>>>(xout, ln4g, ln4b, xn);
  hipMemsetAsync(ksum, 0, (size_t)32 * 64 * 4, stream);
  hipMemsetAsync(ctxb, 0, (size_t)32 * 64 * 64 * 4, stream);
  gemm128<0, 4><<<768, 512, 0, stream>>>(xn, wt_saqkv, b_saqkv, nullptr, qkv,
                                         MQ, 1536, 512, 1024, ksum, 512, TQD);
  ctx_kernel<<<256, 256, 0, stream>>>(qkv + 512, qkv + 1024, ctxb, TQD, 8, 1536);
  qctx_kernel<<<32 * (TQD / 128), 256, 0, stream>>>(qkv, ctxb, ksum, bufD, TQD, 1, 1536);
  gemm128<2, 2><<<512, 512, 0, stream>>>(bufD, wt_sap, sapb, xout, xout,
                                         MQ, 512, 512, 0, nullptr, 0, 0);

  // ---- MLP 2 ----
  ln_kernel<<<MQ / 4, 256, 0, stream>>>(xout, ln5g, ln5b, xn);
  gemm128<1, 4><<<1024, 512, 0, stream>>>(xn, wt_m2w1, m2b1, nullptr, h1,
                                          MQ, 2048, 512, 0, nullptr, 0, 0);
  gemm128<2, 2><<<512, 512, 0, stream>>>(h1, wt_m2w2, m2b2, xout, xout,
                                         MQ, 512, 2048, 0, nullptr, 0, 0);
}

// Round 10
// 550.603 us; speedup vs baseline: 1.3029x; 1.0155x over previous
//
#include <hip/hip_runtime.h>
#include <hip/hip_bf16.h>
#include <math.h>

// Problem constants
#define NBATCH 4
#define TQD 4096
#define TBD 2048
#define CDIM 512
#define NH 8
#define HD 64
#define NINNER 2048

using short8 = __attribute__((ext_vector_type(8))) short;
using f32x4  = __attribute__((ext_vector_type(4))) float;

__device__ __forceinline__ float b2f(short s) {
  return __uint_as_float(((unsigned)(unsigned short)s) << 16);
}
__device__ __forceinline__ short f2b(float f) {
  unsigned u = __float_as_uint(f);
  return (short)((u + 0x7FFFu + ((u >> 16) & 1u)) >> 16);
}
__device__ __forceinline__ unsigned pk2(float a, float b) {
  float2 t; t.x = a; t.y = b;
  __hip_bfloat162 h = __float22bfloat162_rn(t);
  return *(unsigned*)&h;
}
__device__ __forceinline__ float gelu_fast(float x) {
  float x3 = x * x * x;
  float y2 = 1.5957691216f * (x + 0.044715f * x3);
  float e = __expf(y2);
  return x * e / (e + 1.0f);
}
__device__ __forceinline__ void gload16(const short* g, short* l) {
  __builtin_amdgcn_global_load_lds((const __attribute__((address_space(1))) void*)g,
                                   (__attribute__((address_space(3))) void*)l, 16, 0, 0);
}

// ---------------- LayerNorm (fp32 in -> bf16 out), wave-per-row, 4 rows/block
__launch_bounds__(256)
__global__ void ln_kernel(const float* __restrict__ x, const float* __restrict__ g,
                          const float* __restrict__ b, short* __restrict__ out)
{
  int row = blockIdx.x * 4 + (threadIdx.x >> 6);
  int lane = threadIdx.x & 63;
  const float4* xp = (const float4*)(x + (size_t)row * CDIM);
  float4 v0 = xp[lane], v1 = xp[lane + 64];
  float s  = v0.x + v0.y + v0.z + v0.w + v1.x + v1.y + v1.z + v1.w;
  float s2 = v0.x * v0.x + v0.y * v0.y + v0.z * v0.z + v0.w * v0.w
           + v1.x * v1.x + v1.y * v1.y + v1.z * v1.z + v1.w * v1.w;
#pragma unroll
  for (int m = 1; m < 64; m <<= 1) { s += __shfl_xor(s, m); s2 += __shfl_xor(s2, m); }
  float mean = s * (1.0f / CDIM);
  float var  = s2 * (1.0f / CDIM) - mean * mean;
  float inv  = rsqrtf(var + 1e-5f);
  float4 g0 = ((const float4*)g)[lane], g1 = ((const float4*)g)[lane + 64];
  float4 b0 = ((const float4*)b)[lane], b1 = ((const float4*)b)[lane + 64];
  uint2 o0, o1;
  o0.x = pk2((v0.x - mean) * inv * g0.x + b0.x, (v0.y - mean) * inv * g0.y + b0.y);
  o0.y = pk2((v0.z - mean) * inv * g0.z + b0.z, (v0.w - mean) * inv * g0.w + b0.w);
  o1.x = pk2((v1.x - mean) * inv * g1.x + b1.x, (v1.y - mean) * inv * g1.y + b1.y);
  o1.y = pk2((v1.z - mean) * inv * g1.z + b1.z, (v1.w - mean) * inv * g1.w + b1.w);
  uint2* op = (uint2*)(out + (size_t)row * CDIM);
  op[lane] = o0;
  op[lane + 64] = o1;
}

// ---------------- batched transpose+convert: W[K][N] f32 -> Wt[N][K] bf16
struct TcvtDesc {
  const float* src[14];
  short* dst[14];
  int K[14], N[14], nblk[14];
};
__launch_bounds__(256)
__global__ void tcvt_all(TcvtDesc d)
{
  int blk = blockIdx.x, wi = 0;
  while (blk >= d.nblk[wi]) { blk -= d.nblk[wi]; wi++; }
  const float* __restrict__ W = d.src[wi];
  short* __restrict__ Wt = d.dst[wi];
  int K = d.K[wi], N = d.N[wi];
  __shared__ float t[32][33];
  int nbk = K >> 5;
  int bk = blk % nbk, bn = blk / nbk;
  int cx = threadIdx.x & 31, cy = threadIdx.x >> 5;
#pragma unroll
  for (int i = 0; i < 4; i++)
    t[cy + 8 * i][cx] = W[(size_t)(bk * 32 + cy + 8 * i) * N + bn * 32 + cx];
  __syncthreads();
#pragma unroll
  for (int i = 0; i < 4; i++)
    Wt[(size_t)(bn * 32 + cy + 8 * i) * K + bk * 32 + cx] = f2b(t[cx][cy + 8 * i]);
}

#define VMW(n) asm volatile("s_waitcnt vmcnt(" #n ")" ::: "memory");

// ======== 128 x (NF*64) GEMM, BK=32, 2 phases/K-tile, 2 blocks/CU ===========
// r9 schedule (A quad-buf, B triple-buf, stage AB(t+2)@ph0, VMW(L)@ph1) with:
//  - sched_barrier mask 0x0E (VALU|SALU|MFMA may cross; DS/VMEM pinned) so the
//    compiler can interleave MFMA/addr-calc across phase boundaries. Safety:
//    cross-wave publish only requires ds_reads stay after the preceding
//    VMW+barrier (they do; DS pinned); MFMA ordered by SSA deps.
//  - K as template param: NT compile-time, unroll 4, rotating buffer indices
//    constant-fold -> loop VALU collapses.
// EPI: 0 = bf16 + softmax per 64-col head chunk where col<smLimit (NF=2:
// cross-wave-pair exchange via LDS) + fused k-colsum when ksumP!=null
// (cols [csBase,csBase+512)); 1 = gelu bf16; 2 = residual-add fp32.
template<int EPI, int NF, int KK>
__launch_bounds__(512, 4)
__global__ void gemm128(const short* __restrict__ A, const short* __restrict__ Bt,
                        const float* __restrict__ bias, const float* __restrict__ resid,
                        void* __restrict__ outp, int M, int N, int smLimit,
                        float* __restrict__ ksumP, int csBase, int Trows)
{
  constexpr int BUFB = NF * 2048;           // shorts per B buffer
  constexpr int NT = KK >> 5;
  __shared__ short As[4 * 4096];            // 4 bufs x [128][32]
  __shared__ short Bs[3 * BUFB];            // 3 bufs x [NF*64][32]
  int tid = threadIdx.x, lane = tid & 63, wave = tid >> 6;
  int l15 = lane & 15, g = lane >> 4;
  int wr = wave >> 2, wn = wave & 3;
  int nbn = N / (NF * 64);
  int per = gridDim.x >> 3;
  int wg = (blockIdx.x & 7) * per + (blockIdx.x >> 3);
  int bm = wg / nbn, bn = wg % nbn;
  f32x4 acc[4][NF] = {};

  int srcslot = ((lane & 3) ^ ((lane >> 3) & 3)) * 8;
  const short* gA0 = A  + (size_t)(bm * 128 + wave * 16 + (lane >> 2)) * KK + srcslot;
  const short* gB0 = Bt + (size_t)(bn * (NF * 64) + wave * 16 + (lane >> 2)) * KK + srcslot;
  const short* gB1 = gB0 + (size_t)128 * KK;   // NF=4 only
  short* lA = As + wave * 512;
  short* lB = Bs + wave * 512;

  int rsw = (g ^ ((l15 >> 1) & 3)) * 8;
  const short* raB = As + (wr * 64 + l15) * 32 + rsw;
  const short* rbB = Bs + (wn * (NF * 16) + l15) * 32 + rsw;

  short8 af[2], bfr[NF];

#define STGA1(T) gload16(gA0 + (size_t)(T) * 32, lA + ((T) & 3) * 4096);
#define STGB1(T, BI) { \
    gload16(gB0 + (size_t)(T) * 32, lB + (BI) * BUFB); \
    if constexpr (NF == 4) gload16(gB1 + (size_t)(T) * 32, lB + (BI) * BUFB + 4096); }
#define RDB1(BI) { \
    const short* bp = rbB + (BI) * BUFB; \
    _Pragma("unroll") for (int n = 0; n < NF; n++) \
      bfr[n] = *(const short8*)(bp + n * 512); }
#define RDA1(T, q) { \
    const short* ap = raB + ((T) & 3) * 4096 + (q) * 1024; \
    af[0] = *(const short8*)(ap); af[1] = *(const short8*)(ap + 512); }
#define MFMAQ1(q) { \
    __builtin_amdgcn_s_setprio(1); \
    _Pragma("unroll") for (int n = 0; n < NF; n++) { \
      acc[2*(q)][n]   = __builtin_amdgcn_mfma_f32_16x16x32_bf16(bfr[n], af[0], acc[2*(q)][n], 0, 0, 0); \
      acc[2*(q)+1][n] = __builtin_amdgcn_mfma_f32_16x16x32_bf16(bfr[n], af[1], acc[2*(q)+1][n], 0, 0, 0); } \
    __builtin_amdgcn_s_setprio(0); }
#define VMW_S { if constexpr (NF == 4) { VMW(3) } else { VMW(2) } }
#define BARX1 { __builtin_amdgcn_s_barrier(); __builtin_amdgcn_sched_barrier(0x0E); }
#define BAR21 { __builtin_amdgcn_s_barrier(); }

  // prologue: AB(0), AB(1) -> 2L outstanding; VMW(L) drains AB(0)
  STGA1(0); STGB1(0, 0);
  STGA1(1); STGB1(1, 1);
  VMW_S;
  BAR21;

  int bR = 0, bS = 2;                       // t%3, (t+2)%3 (rotating, foldable)
#pragma unroll 4
  for (int t = 0; t < NT - 2; ++t) {
    RDB1(bR); RDA1(t, 0); STGA1(t + 2); STGB1(t + 2, bS); BARX1; MFMAQ1(0); BAR21;
    RDA1(t, 1); VMW_S;                                    BARX1; MFMAQ1(1); BAR21;
    bR = (bR == 2) ? 0 : bR + 1;
    bS = (bS == 2) ? 0 : bS + 1;
  }
  { // peel tile NT-2: no staging; VMW(0) publishes NT-1
    constexpr int B2 = (NT - 2) % 3;
    RDB1(B2); RDA1(NT - 2, 0); BARX1; MFMAQ1(0); BAR21;
    RDA1(NT - 2, 1); VMW(0);   BARX1; MFMAQ1(1); BAR21;
  }
  { // peel tile NT-1
    constexpr int B1 = (NT - 1) % 3;
    RDB1(B1); RDA1(NT - 1, 0); BARX1; MFMAQ1(0); BAR21;
    RDA1(NT - 1, 1);           BARX1; MFMAQ1(1);
  }
#undef STGA1
#undef STGB1
#undef RDB1
#undef RDA1
#undef MFMAQ1
#undef VMW_S
#undef BARX1
#undef BAR21

  int row0 = bm * 128 + wr * 64, col0 = bn * (NF * 64) + wn * (NF * 16);
#pragma unroll
  for (int n = 0; n < NF; n++) {
    f32x4 bz = *(const f32x4*)(bias + col0 + n * 16 + g * 4);
#pragma unroll
    for (int m = 0; m < 4; m++)
#pragma unroll
      for (int r = 0; r < 4; r++) acc[m][n][r] += bz[r];
  }
  if (EPI == 0) {
    bool insm = (bn * (NF * 64) < smLimit);    // block-uniform
    if constexpr (NF == 4) {
      if (insm) {
#pragma unroll
        for (int m = 0; m < 4; m++) {
          float mx = acc[m][0][0];
#pragma unroll
          for (int n = 0; n < 4; n++)
#pragma unroll
            for (int r = 0; r < 4; r++) mx = fmaxf(mx, acc[m][n][r]);
          mx = fmaxf(mx, __shfl_xor(mx, 16));
          mx = fmaxf(mx, __shfl_xor(mx, 32));
          float s = 0.0f;
#pragma unroll
          for (int n = 0; n < 4; n++)
#pragma unroll
            for (int r = 0; r < 4; r++) {
              float e = __expf(acc[m][n][r] - mx);
              acc[m][n][r] = e; s += e;
            }
          s += __shfl_xor(s, 16);
          s += __shfl_xor(s, 32);
          float inv = 1.0f / s;
#pragma unroll
          for (int n = 0; n < 4; n++)
#pragma unroll
            for (int r = 0; r < 4; r++) acc[m][n][r] *= inv;
        }
      }
    } else {
      // NF=2: 64-col head chunk spans wave pair (wave, wave^1). Exchange
      // partial max/sum via LDS (As reused; __syncthreads provides fences).
      if (insm) {
        float* xch = (float*)As;               // [8 waves][4 m][16 l15]
        float pm[4], ps[4];
#pragma unroll
        for (int m = 0; m < 4; m++) {
          float mx = acc[m][0][0];
#pragma unroll
          for (int n = 0; n < 2; n++)
#pragma unroll
            for (int r = 0; r < 4; r++) mx = fmaxf(mx, acc[m][n][r]);
          mx = fmaxf(mx, __shfl_xor(mx, 16));
          mx = fmaxf(mx, __shfl_xor(mx, 32));
          pm[m] = mx;
        }
        __syncthreads();
        if (g == 0)
#pragma unroll
          for (int m = 0; m < 4; m++) xch[wave * 64 + m * 16 + l15] = pm[m];
        __syncthreads();
#pragma unroll
        for (int m = 0; m < 4; m++)
          pm[m] = fmaxf(pm[m], xch[(wave ^ 1) * 64 + m * 16 + l15]);
#pragma unroll
        for (int m = 0; m < 4; m++) {
          float s = 0.0f;
#pragma unroll
          for (int n = 0; n < 2; n++)
#pragma unroll
            for (int r = 0; r < 4; r++) {
              float e = __expf(acc[m][n][r] - pm[m]);
              acc[m][n][r] = e; s += e;
            }
          s += __shfl_xor(s, 16);
          s += __shfl_xor(s, 32);
          ps[m] = s;
        }
        __syncthreads();
        if (g == 0)
#pragma unroll
          for (int m = 0; m < 4; m++) xch[wave * 64 + m * 16 + l15] = ps[m];
        __syncthreads();
#pragma unroll
        for (int m = 0; m < 4; m++) {
          float inv = 1.0f / (ps[m] + xch[(wave ^ 1) * 64 + m * 16 + l15]);
#pragma unroll
          for (int n = 0; n < 2; n++)
#pragma unroll
            for (int r = 0; r < 4; r++) acc[m][n][r] *= inv;
        }
      }
    }
  }
  if (EPI == 0 && ksumP != nullptr) {
    unsigned rel = (unsigned)(col0 - csBase);
    if (rel < 512u) {
      float* kp = ksumP + ((row0 / Trows) * 8 + (int)(rel >> 6)) * 64 + (int)(rel & 63u);
#pragma unroll
      for (int n = 0; n < NF; n++) {
        f32x4 s = acc[0][n];
#pragma unroll
        for (int m = 1; m < 4; m++)
#pragma unroll
          for (int r = 0; r < 4; r++) s[r] += acc[m][n][r];
#pragma unroll
        for (int msk = 1; msk < 16; msk <<= 1)
#pragma unroll
          for (int r = 0; r < 4; r++) s[r] += __shfl_xor(s[r], msk);
        if (l15 == 0)
#pragma unroll
          for (int r = 0; r < 4; r++)
            atomicAdd(kp + n * 16 + g * 4 + r, s[r]);
      }
    }
  }
  if (EPI == 1) {
#pragma unroll
    for (int m = 0; m < 4; m++)
#pragma unroll
      for (int n = 0; n < NF; n++)
#pragma unroll
        for (int r = 0; r < 4; r++) acc[m][n][r] = gelu_fast(acc[m][n][r]);
  }
#pragma unroll
  for (int m = 0; m < 4; m++) {
    int row = row0 + m * 16 + l15;
#pragma unroll
    for (int n = 0; n < NF; n++) {
      size_t base = (size_t)row * N + col0 + n * 16 + g * 4;
      if (EPI == 2) {
        f32x4 rv = *(const f32x4*)(resid + base);
        f32x4 o;
#pragma unroll
        for (int r = 0; r < 4; r++) o[r] = rv[r] + acc[m][n][r];
        *(f32x4*)((float*)outp + base) = o;
      } else {
        uint2 u;
        u.x = pk2(acc[m][n][0], acc[m][n][1]);
        u.y = pk2(acc[m][n][2], acc[m][n][3]);
        *(uint2*)((unsigned short*)outp + base) = u;
      }
    }
  }
}

// ---------------- ctx += k^T v per (b,h); grid = 32*parts, atomics into zeroed ctx
#define LDC 40
__launch_bounds__(256)
__global__ void ctx_kernel(const short* __restrict__ k, const short* __restrict__ v,
                           float* __restrict__ ctx, int T, int parts, int SD)
{
  __shared__ short kT[4][64 * LDC];
  __shared__ short vT[4][64 * LDC];
  int bh = blockIdx.x & 31, part = blockIdx.x >> 5;
  int b = bh >> 3, h = bh & 7;
  int tid = threadIdx.x, lane = tid & 63, wave = tid >> 6;
  int l15 = lane & 15, g = lane >> 4;
  int tlen = T / (4 * parts);
  int tbeg = (part * 4 + wave) * tlen;
  f32x4 acc[4][4] = {};
  short* myK = kT[wave];
  short* myV = vT[wave];
  for (int t0 = tbeg; t0 < tbeg + tlen; t0 += 32) {
#pragma unroll
    for (int j = 0; j < 4; j++) {
      int c = lane + j * 64;
      int r = c >> 3, d0 = (c & 7) * 8;
      short8 kv = *(const short8*)(k + (size_t)(b * T + t0 + r) * SD + h * 64 + d0);
      short8 vv = *(const short8*)(v + (size_t)(b * T + t0 + r) * SD + h * 64 + d0);
#pragma unroll
      for (int i = 0; i < 8; i++) {
        myK[(d0 + i) * LDC + r] = kv[i];
        myV[(d0 + i) * LDC + r] = vv[i];
      }
    }
    __syncthreads();
    short8 af[4], bfr[4];
#pragma unroll
    for (int m = 0; m < 4; m++) af[m]  = *(const short8*)(myK + (m * 16 + l15) * LDC + g * 8);
#pragma unroll
    for (int n = 0; n < 4; n++) bfr[n] = *(const short8*)(myV + (n * 16 + l15) * LDC + g * 8);
#pragma unroll
    for (int m = 0; m < 4; m++)
#pragma unroll
      for (int n = 0; n < 4; n++)
        acc[m][n] = __builtin_amdgcn_mfma_f32_16x16x32_bf16(af[m], bfr[n], acc[m][n], 0, 0, 0);
    __syncthreads();
  }
  float* cp = ctx + (size_t)bh * 64 * 64;
#pragma unroll
  for (int m = 0; m < 4; m++)
#pragma unroll
    for (int n = 0; n < 4; n++)
#pragma unroll
      for (int r = 0; r < 4; r++)
        atomicAdd(cp + (m * 16 + g * 4 + r) * 64 + (n * 16 + l15), acc[m][n][r]);
}

// ---------------- out[t,:] = q[t,:] + sum_br dinv(t) * (q[t,:] @ ctx[br])
#define LQ 72
__launch_bounds__(256)
__global__ void qctx_kernel(const short* __restrict__ q,
                            const float* __restrict__ ctx,   // [nb][32][64][64]
                            const float* __restrict__ ksum,  // [nb][32][64]
                            short* __restrict__ outp, int T, int nb, int SD)
{
  __shared__ short qs[128 * LQ];
  __shared__ short cT[2][64 * LQ];
  __shared__ float dls[2][128];
  int ntb = T >> 7;
  int bh = blockIdx.x / ntb, tq = blockIdx.x % ntb;
  int b = bh >> 3, h = bh & 7;
  int tid = threadIdx.x, lane = tid & 63, wave = tid >> 6;
  int l15 = lane & 15, g = lane >> 4;
  size_t qbase = (size_t)(b * T + tq * 128) * SD + h * 64;
  size_t obase = (size_t)(b * T + tq * 128) * CDIM + h * 64;

#pragma unroll
  for (int j = 0; j < 4; j++) {
    int c = tid + j * 256;
    int r = c >> 3, d0 = (c & 7) * 8;
    *(short8*)(qs + r * LQ + d0) = *(const short8*)(q + qbase + (size_t)r * SD + d0);
  }
  for (int br = 0; br < nb; br++) {
    const float* cp = ctx + ((size_t)br * 32 + bh) * 4096;
#pragma unroll
    for (int j = 0; j < 16; j++) {
      int e2 = tid + j * 256;
      int dd = e2 >> 6, ee = e2 & 63;
      cT[br][ee * LQ + dd] = f2b(cp[e2]);
    }
  }
  __syncthreads();

  int r0 = wave * 32;
  for (int br = 0; br < nb; br++) {
    int row = r0 + (lane >> 1);
    int dbase = (lane & 1) * 32;
    const float* kp = ksum + ((size_t)br * 32 + bh) * 64 + dbase;
    float s = 0.0f;
#pragma unroll
    for (int d = 0; d < 32; d++)
      s += b2f(qs[row * LQ + dbase + d]) * kp[d];
    s += __shfl_xor(s, 1);
    if (!(lane & 1)) dls[br][row] = 1.0f / fmaxf(s, 1e-9f);
  }

  short8 af[2][2];
#pragma unroll
  for (int m = 0; m < 2; m++)
#pragma unroll
    for (int kk = 0; kk < 2; kk++)
      af[m][kk] = *(const short8*)(qs + (r0 + m * 16 + l15) * LQ + kk * 32 + g * 8);

  float ofin[2][4][4];
#pragma unroll
  for (int m = 0; m < 2; m++)
#pragma unroll
    for (int n = 0; n < 4; n++)
#pragma unroll
      for (int r = 0; r < 4; r++)
        ofin[m][n][r] = b2f(qs[(r0 + m * 16 + g * 4 + r) * LQ + n * 16 + l15]);

  for (int br = 0; br < nb; br++) {
    f32x4 acc[2][4] = {};
#pragma unroll
    for (int kk = 0; kk < 2; kk++) {
      short8 bfr[4];
#pragma unroll
      for (int n = 0; n < 4; n++)
        bfr[n] = *(const short8*)(cT[br] + (n * 16 + l15) * LQ + kk * 32 + g * 8);
#pragma unroll
      for (int m = 0; m < 2; m++)
#pragma unroll
        for (int n = 0; n < 4; n++)
          acc[m][n] = __builtin_amdgcn_mfma_f32_16x16x32_bf16(af[m][kk], bfr[n], acc[m][n], 0, 0, 0);
    }
#pragma unroll
    for (int m = 0; m < 2; m++)
#pragma unroll
      for (int n = 0; n < 4; n++)
#pragma unroll
        for (int r = 0; r < 4; r++)
          ofin[m][n][r] += dls[br][r0 + m * 16 + g * 4 + r] * acc[m][n][r];
  }

#pragma unroll
  for (int m = 0; m < 2; m++)
#pragma unroll
    for (int n = 0; n < 4; n++)
#pragma unroll
      for (int r = 0; r < 4; r++) {
        int row = r0 + m * 16 + g * 4 + r;
        int col = n * 16 + l15;
        outp[obase + (size_t)row * CDIM + col] = f2b(ofin[m][n][r]);
      }
}

extern "C" void kernel_launch(void* const* d_in, const int* in_sizes, int n_in,
                              void* d_out, int out_size, void* d_ws, size_t ws_size,
                              hipStream_t stream)
{
  (void)in_sizes; (void)n_in; (void)out_size; (void)ws_size;
  const float* x     = (const float*)d_in[0];
  const float* y0    = (const float*)d_in[1];
  const float* y1    = (const float*)d_in[2];
  const float* ln1g  = (const float*)d_in[3];
  const float* ln1b  = (const float*)d_in[4];
  const float* ln20g = (const float*)d_in[5];
  const float* ln20b = (const float*)d_in[6];
  const float* ln21g = (const float*)d_in[7];
  const float* ln21b = (const float*)d_in[8];
  const float* ln3g  = (const float*)d_in[9];
  const float* ln3b  = (const float*)d_in[10];
  const float* ln4g  = (const float*)d_in[11];
  const float* ln4b  = (const float*)d_in[12];
  const float* ln5g  = (const float*)d_in[13];
  const float* ln5b  = (const float*)d_in[14];
  const float* caqw  = (const float*)d_in[15];
  const float* caqb  = (const float*)d_in[16];
  const float* cak0w = (const float*)d_in[17];
  const float* cak0b = (const float*)d_in[18];
  const float* cav0w = (const float*)d_in[19];
  const float* cav0b = (const float*)d_in[20];
  const float* cak1w = (const float*)d_in[21];
  const float* cak1b = (const float*)d_in[22];
  const float* cav1w = (const float*)d_in[23];
  const float* cav1b = (const float*)d_in[24];
  const float* capw  = (const float*)d_in[25];
  const float* capb  = (const float*)d_in[26];
  const float* saqw  = (const float*)d_in[27];
  const float* saqb  = (const float*)d_in[28];
  const float* sakw  = (const float*)d_in[29];
  const float* sakb  = (const float*)d_in[30];
  const float* savw  = (const float*)d_in[31];
  const float* savb  = (const float*)d_in[32];
  const float* sapw  = (const float*)d_in[33];
  const float* sapb  = (const float*)d_in[34];
  const float* m1w1  = (const float*)d_in[35];
  const float* m1b1  = (const float*)d_in[36];
  const float* m1w2  = (const float*)d_in[37];
  const float* m1b2  = (const float*)d_in[38];
  const float* m2w1  = (const float*)d_in[39];
  const float* m2b1  = (const float*)d_in[40];
  const float* m2w2  = (const float*)d_in[41];
  const float* m2b2  = (const float*)d_in[42];
  float* xout = (float*)d_out;

  char* p = (char*)d_ws;
  size_t off = 0;
  auto take = [&](size_t bytes) {
    char* r = p + off;
    off += (bytes + 255) & ~(size_t)255;
    return r;
  };
  const size_t W512 = (size_t)512 * 512 * 2;
  const size_t WMLP = (size_t)2048 * 512 * 2;
  short* wt_caq   = (short*)take(W512);
  short* wt_cakv0 = (short*)take(2 * W512);       // [k;v] 1024x512
  short* wt_cakv1 = (short*)take(2 * W512);
  short* wt_cap   = (short*)take(W512);
  short* wt_saqkv = (short*)take(3 * W512);       // [q;k;v] 1536x512
  short* wt_sap   = (short*)take(W512);
  short* wt_m1w1  = (short*)take(WMLP);
  short* wt_m1w2  = (short*)take(WMLP);
  short* wt_m2w1  = (short*)take(WMLP);
  short* wt_m2w2  = (short*)take(WMLP);
  float* b_saqkv  = (float*)take(1536 * 4);
  float* b_cakv0  = (float*)take(1024 * 4);
  float* b_cakv1  = (float*)take(1024 * 4);
  short* xn   = (short*)take((size_t)16384 * 512 * 2);
  short* bufD = (short*)take((size_t)16384 * 512 * 2);
  short* big  = (short*)take((size_t)16384 * 1536 * 2);   // CA: q@0, kv@+8M shorts; SA: qkv
  short* h1   = (short*)take((size_t)16384 * 2048 * 2);
  float* ksum = (float*)take((size_t)2 * 32 * 64 * 4);
  float* ctxb = (float*)take((size_t)2 * 32 * 64 * 64 * 4);

  short* q_ca  = big;
  short* kv_ca = big + (size_t)8 * 1024 * 1024;
  short* qkv   = big;

  const int MQ  = NBATCH * TQD;   // 16384
  const int MKV = NBATCH * TBD;   // 8192

  // ---- weight transpose+convert (single batched launch) ----
  {
    TcvtDesc d;
    const float* srcs[14] = {caqw, cak0w, cav0w, cak1w, cav1w, capw,
                             saqw, sakw, savw, sapw, m1w1, m1w2, m2w1, m2w2};
    short* dsts[14] = {wt_caq, wt_cakv0, wt_cakv0 + 512 * 512,
                       wt_cakv1, wt_cakv1 + 512 * 512, wt_cap,
                       wt_saqkv, wt_saqkv + 512 * 512, wt_saqkv + 2 * 512 * 512, wt_sap,
                       wt_m1w1, wt_m1w2, wt_m2w1, wt_m2w2};
    int Ks[14] = {512,512,512,512,512,512,512,512,512,512, 512,2048,512,2048};
    int Ns[14] = {512,512,512,512,512,512,512,512,512,512, 2048,512,2048,512};
    int total = 0;
    for (int i = 0; i < 14; i++) {
      d.src[i] = srcs[i]; d.dst[i] = dsts[i]; d.K[i] = Ks[i]; d.N[i] = Ns[i];
      d.nblk[i] = (Ks[i] >> 5) * (Ns[i] >> 5);
      total += d.nblk[i];
    }
    tcvt_all<<<total, 256, 0, stream>>>(d);
  }
  // ---- bias concats ----
  hipMemcpyAsync(b_saqkv,        saqb,  512 * 4, hipMemcpyDeviceToDevice, stream);
  hipMemcpyAsync(b_saqkv + 512,  sakb,  512 * 4, hipMemcpyDeviceToDevice, stream);
  hipMemcpyAsync(b_saqkv + 1024, savb,  512 * 4, hipMemcpyDeviceToDevice, stream);
  hipMemcpyAsync(b_cakv0,        cak0b, 512 * 4, hipMemcpyDeviceToDevice, stream);
  hipMemcpyAsync(b_cakv0 + 512,  cav0b, 512 * 4, hipMemcpyDeviceToDevice, stream);
  hipMemcpyAsync(b_cakv1,        cak1b, 512 * 4, hipMemcpyDeviceToDevice, stream);
  hipMemcpyAsync(b_cakv1 + 512,  cav1b, 512 * 4, hipMemcpyDeviceToDevice, stream);

  // ---- cross-attention ----
  ln_kernel<<<MQ / 4, 256, 0, stream>>>(x, ln1g, ln1b, xn);
  hipMemsetAsync(ksum, 0, (size_t)2 * 32 * 64 * 4, stream);
  hipMemsetAsync(ctxb, 0, (size_t)2 * 32 * 64 * 64 * 4, stream);
  gemm128<0, 2, 512><<<512, 512, 0, stream>>>(xn, wt_caq, caqb, nullptr, q_ca,
                                              MQ, 512, 512, nullptr, 0, 0);
  for (int br = 0; br < 2; br++) {
    const float* yy = br ? y1 : y0;
    const float* lg = br ? ln21g : ln20g;
    const float* lb = br ? ln21b : ln20b;
    const short* wk = br ? wt_cakv1 : wt_cakv0;
    const float* bk = br ? b_cakv1 : b_cakv0;
    ln_kernel<<<MKV / 4, 256, 0, stream>>>(yy, lg, lb, bufD);
    gemm128<0, 2, 512><<<512, 512, 0, stream>>>(bufD, wk, bk, nullptr, kv_ca,
                                                MKV, 1024, 512,
                                                ksum + (size_t)br * 2048, 0, TBD);
    ctx_kernel<<<256, 256, 0, stream>>>(kv_ca, kv_ca + 512,
                                        ctxb + (size_t)br * 32 * 4096, TBD, 8, 1024);
  }
  qctx_kernel<<<32 * (TQD / 128), 256, 0, stream>>>(q_ca, ctxb, ksum, bufD, TQD, 2, 512);
  gemm128<2, 2, 512><<<512, 512, 0, stream>>>(bufD, wt_cap, capb, x, xout,
                                              MQ, 512, 0, nullptr, 0, 0);

  // ---- MLP 1 ----
  ln_kernel<<<MQ / 4, 256, 0, stream>>>(xout, ln3g, ln3b, xn);
  gemm128<1, 4, 512><<<1024, 512, 0, stream>>>(xn, wt_m1w1, m1b1, nullptr, h1,
                                               MQ, 2048, 0, nullptr, 0, 0);
  gemm128<2, 2, 2048><<<512, 512, 0, stream>>>(h1, wt_m1w2, m1b2, xout, xout,
                                               MQ, 512, 0, nullptr, 0, 0);

  // ---- self-attention (fused q|k|v projection; k-colsum fused) ----
  ln_kernel<<<MQ / 4, 256, 0, stream>>>(xout, ln4g, ln4b, xn);
  hipMemsetAsync(ksum, 0, (size_t)32 * 64 * 4, stream);
  hipMemsetAsync(ctxb, 0, (size_t)32 * 64 * 64 * 4, stream);
  gemm128<0, 4, 512><<<768, 512, 0, stream>>>(xn, wt_saqkv, b_saqkv, nullptr, qkv,
                                              MQ, 1536, 1024, ksum, 512, TQD);
  ctx_kernel<<<256, 256, 0, stream>>>(qkv + 512, qkv + 1024, ctxb, TQD, 8, 1536);
  qctx_kernel<<<32 * (TQD / 128), 256, 0, stream>>>(qkv, ctxb, ksum, bufD, TQD, 1, 1536);
  gemm128<2, 2, 512><<<512, 512, 0, stream>>>(bufD, wt_sap, sapb, xout, xout,
                                              MQ, 512, 0, nullptr, 0, 0);

  // ---- MLP 2 ----
  ln_kernel<<<MQ / 4, 256, 0, stream>>>(xout, ln5g, ln5b, xn);
  gemm128<1, 4, 512><<<1024, 512, 0, stream>>>(xn, wt_m2w1, m2b1, nullptr, h1,
                                               MQ, 2048, 0, nullptr, 0, 0);
  gemm128<2, 2, 2048><<<512, 512, 0, stream>>>(h1, wt_m2w2, m2b2, xout, xout,
                                               MQ, 512, 0, nullptr, 0, 0);
}